// Round 1
// 3231.414 us; speedup vs baseline: 1.1093x; 1.1093x over previous
//
#include <hip/hip_runtime.h>
#include <cstdint>
#include <cstddef>

typedef unsigned short u16;
typedef unsigned int   u32;
typedef __attribute__((ext_vector_type(8))) short s16x8;
typedef __attribute__((ext_vector_type(4))) float fx4;

// ---------- helpers ----------
__device__ __forceinline__ u16 f2bf(float x){
  u32 u = __float_as_uint(x);
  u32 r = (u + 0x7fffu + ((u >> 16) & 1u)) >> 16;   // RNE
  return (u16)r;
}
__device__ __forceinline__ float bf2f(u16 x){
  return __uint_as_float(((u32)x) << 16);
}
__device__ __forceinline__ float rcp_(float x){ return __builtin_amdgcn_rcpf(x); }
__device__ __forceinline__ float sigm(float x){ return rcp_(1.f + __expf(-x)); }
__device__ __forceinline__ float tanh_(float x){
  x = fminf(fmaxf(x, -15.f), 15.f);
  float e = __expf(2.f*x);
  return (e-1.f)*rcp_(e+1.f);
}
__device__ __forceinline__ u32 cvt_pk_bf16(float lo, float hi){
  u32 d;
  asm("v_cvt_pk_bf16_f32 %0, %1, %2" : "=v"(d) : "v"(lo), "v"(hi));
  return d;
}
__device__ __forceinline__ void gl_lds16(const u16* g, u16* l){
  __builtin_amdgcn_global_load_lds((__attribute__((address_space(1))) void*)(void*)g,
                                   (__attribute__((address_space(3))) void*)(void*)l,
                                   16, 0, 0);
}
__device__ __forceinline__ fx4 mfma16(s16x8 a, s16x8 b, fx4 c){
  return __builtin_amdgcn_mfma_f32_16x16x32_bf16(a, b, c, 0, 0, 0);
}

// ---------- generic bf16 GEMM  C[M][N] = A[M][K] * Bt[N][K]^T  (m97 structure) ----------
// MODE 0: fp32 row-major C.  MODE 2: bf16 scatter into Gt[t][dir][b][624] token layout.
template<int MODE>
__global__ __launch_bounds__(256, 2) void gemm_bt(
    const u16* __restrict__ A, const u16* __restrict__ Bt, void* __restrict__ Cp,
    int lda, int ldb, int ldc, int K)
{
  __shared__ u16 As[128*32];
  __shared__ u16 Bs[128*32];
  const int t    = threadIdx.x;
  const int lane = t & 63;
  const int wave = t >> 6;
  const int mw   = (wave >> 1) * 64;
  const int nw   = (wave & 1) * 64;
  const int m0   = blockIdx.y * 128;
  const int n0   = blockIdx.x * 128;
  const int col  = lane & 15, quad = lane >> 4;

  fx4 acc[4][4];
#pragma unroll
  for (int i=0;i<4;i++)
#pragma unroll
    for (int j=0;j<4;j++) acc[i][j] = fx4{0.f,0.f,0.f,0.f};

  const int u0 = t, u1 = t + 256;
  const int ar0 = u0 >> 2, ac0 = (u0 & 3) * 8;
  const int ar1 = u1 >> 2, ac1 = (u1 & 3) * 8;
  const u16* gA0 = A  + (size_t)(m0 + ar0) * lda + ac0;
  const u16* gA1 = A  + (size_t)(m0 + ar1) * lda + ac1;
  const u16* gB0 = Bt + (size_t)(n0 + ar0) * ldb + ac0;
  const u16* gB1 = Bt + (size_t)(n0 + ar1) * ldb + ac1;
  u16* lA0 = As + u0*8; u16* lA1 = As + u1*8;
  u16* lB0 = Bs + u0*8; u16* lB1 = Bs + u1*8;
  const u16* pa = As + (mw + col)*32 + quad*8;
  const u16* pb = Bs + (nw + col)*32 + quad*8;

  for (int k0 = 0; k0 < K; k0 += 32){
    gl_lds16(gA0 + k0, lA0);
    gl_lds16(gA1 + k0, lA1);
    gl_lds16(gB0 + k0, lB0);
    gl_lds16(gB1 + k0, lB1);
    __syncthreads();
    s16x8 af[4], bf[4];
#pragma unroll
    for (int mt=0; mt<4; ++mt) af[mt] = *(const s16x8*)(pa + mt*512);
#pragma unroll
    for (int nt=0; nt<4; ++nt) bf[nt] = *(const s16x8*)(pb + nt*512);
#pragma unroll
    for (int mt=0; mt<4; ++mt)
#pragma unroll
      for (int nt=0; nt<4; ++nt)
        acc[mt][nt] = mfma16(af[mt], bf[nt], acc[mt][nt]);
    __syncthreads();
  }
#pragma unroll
  for (int mt=0; mt<4; ++mt)
#pragma unroll
    for (int nt=0; nt<4; ++nt)
#pragma unroll
      for (int i=0; i<4; ++i){
        int m = m0 + mw + mt*16 + quad*4 + i;
        int n = n0 + nw + nt*16 + col;
        float v = acc[mt][nt][i];
        if (MODE == 0){
          ((float*)Cp)[(size_t)m*ldc + n] = v;
        } else {
          if (n < 1248){
            int dir = (n >= 624) ? 1 : 0;
            int r   = n - dir*624;
            int tt  = m >> 4, b = m & 15;
            ((u16*)Cp)[((size_t)((tt*2 + dir)*16 + b))*624 + r] = f2bf(v);
          }
        }
      }
}

// ---------- weight prep ----------
__global__ void k_build_wfused(const float* __restrict__ gW, const float* __restrict__ gWhh,
                               u16* __restrict__ out){
  int k = blockIdx.x*256 + threadIdx.x;   // 0..2047
  int n = blockIdx.y;                     // 0..10111
  float v = 0.f;
  if (k < 2000){
    if (n < 4000)       v = gW  [(size_t)n*2000 + k];
    else if (n < 10000) v = gWhh[(size_t)(n-4000)*2000 + k];
  }
  out[(size_t)n*2048 + k] = f2bf(v);
}
__global__ void k_build_wiht(const float* __restrict__ W, u16* __restrict__ out){
  int k = blockIdx.x*256 + threadIdx.x;
  int n = blockIdx.y;                     // 0..6015
  float v = (k < 2000 && n < 6000) ? W[(size_t)n*2000 + k] : 0.f;
  out[(size_t)n*2048 + k] = f2bf(v);
}
// token Wih; columns n = dir*624 + g*208 + j (j<200 real). bih folded at
// input col 100 (layer0) / 400 (layers 1,2).
__global__ void k_build_wtok(const float* __restrict__ gw, const float* __restrict__ bih,
                             u16* __restrict__ out){
  size_t idx = (size_t)blockIdx.x*256 + threadIdx.x;
  if (idx >= (size_t)3*1280*416) return;
  int k = (int)(idx % 416);
  int n = (int)((idx/416) % 1280);
  int l = (int)(idx/(416*1280));
  float v = 0.f;
  int dir = -1, r = 0;
  if (n < 624){ dir = 0; r = n; }
  else if (n < 1248){ dir = 1; r = n - 624; }
  if (dir >= 0){
    int g = r / 208, j = r % 208;
    if (j < 200){
      int row = (l*2 + dir)*600 + g*200 + j;
      int kreal = (l == 0) ? 100 : 400;
      if (k < kreal)       v = gw[(size_t)row*400 + k];
      else if (k == kreal) v = bih[row];
    }
  }
  out[idx] = f2bf(v);
}

// ---------- CSR ----------
__global__ void k_csr1(const int* __restrict__ dst, int* __restrict__ offs,
                       int* __restrict__ cursor){
  __shared__ int c0[2048];
  __shared__ int c1[2048];
  int tid = threadIdx.x; // 1024
  c0[tid] = 0; c0[tid+1024] = 0;
  __syncthreads();
  for (int e = tid; e < 16000; e += 1024) atomicAdd(&c0[dst[e]], 1);
  __syncthreads();
  int* s = c0; int* d = c1;
  for (int off = 1; off < 2048; off <<= 1){
    for (int i = tid; i < 2048; i += 1024){
      int v = s[i];
      if (i >= off) v += s[i-off];
      d[i] = v;
    }
    __syncthreads();
    int* tmp = s; s = d; d = tmp;
  }
  for (int i = tid; i < 2048; i += 1024){
    int ex = (i == 0) ? 0 : s[i-1];
    if (i <= 2000) offs[i] = ex;
    if (i < 2000)  cursor[i] = ex;
  }
}
__global__ void k_csr2(const int* __restrict__ src, const int* __restrict__ dst,
                       const int* __restrict__ et, int* __restrict__ cursor,
                       int* __restrict__ eidx){
  int e = blockIdx.x*256 + threadIdx.x;
  if (e >= 16000) return;
  int pos = atomicAdd(&cursor[dst[e]], 1);
  eidx[pos] = (src[e] << 1) | (et[e] & 1);
}

// ---------- GGNN pieces ----------
__global__ void k_init_h0(const float* __restrict__ feats, float* __restrict__ h,
                          u16* __restrict__ hb0){
  int j = blockIdx.x*256 + threadIdx.x;  // 0..2047
  int m = blockIdx.y;                    // 0..2047
  float v = (m < 2000 && j < 100) ? feats[(size_t)m*100 + j] : 0.f;
  if (m < 2000 && j < 2000) h[(size_t)m*2000 + j] = v;
  if (j < 128) hb0[(size_t)m*128 + j] = f2bf(v);
}
__global__ void k_gather(const float* __restrict__ C1, const int* __restrict__ offs,
                         const int* __restrict__ eidx, const float* __restrict__ gb,
                         u16* __restrict__ ab){
  int c = blockIdx.y*256 + threadIdx.x;  // 0..2047
  int n = blockIdx.x;                    // 0..2047
  float s = 0.f;
  if (n < 2000 && c < 2000){
    int p0 = offs[n], p1 = offs[n+1];
    for (int p = p0; p < p1; ++p){
      int pk = eidx[p];
      int sn = pk >> 1, e = pk & 1;
      s += C1[(size_t)sn*10112 + e*2000 + c] + gb[(size_t)e*2000 + c];
    }
  }
  ab[(size_t)n*2048 + c] = f2bf(s);
}
__global__ void k_gru_elem(const float* __restrict__ C1, const float* __restrict__ C2,
                           const float* __restrict__ bih, const float* __restrict__ bhh,
                           float* __restrict__ h, u16* __restrict__ hb){
  int j = blockIdx.x*256 + threadIdx.x;  // 0..2047
  int m = blockIdx.y;                    // 0..2047
  float hv = 0.f;
  if (m < 2000 && j < 2000){
    const float* c1 = C1 + (size_t)m*10112;
    const float* c2 = C2 + (size_t)m*6016;
    float gir = c2[j]        + bih[j];
    float giz = c2[2000 + j] + bih[2000 + j];
    float gin = c2[4000 + j] + bih[4000 + j];
    float ghr = c1[4000 + j] + bhh[j];
    float ghz = c1[6000 + j] + bhh[2000 + j];
    float ghn = c1[8000 + j] + bhh[4000 + j];
    float r  = sigm(gir + ghr);
    float z  = sigm(giz + ghz);
    float nn = tanh_(gin + r*ghn);
    float ho = h[(size_t)m*2000 + j];
    hv = (1.f - z)*nn + z*ho;
    h[(size_t)m*2000 + j] = hv;
  }
  hb[(size_t)m*2048 + j] = f2bf(hv);
}
__global__ void k_ranges(const int* __restrict__ batch, int* __restrict__ bstart){
  int i = blockIdx.x*1024 + threadIdx.x;
  if (i < 2000){
    int cur  = batch[i];
    int prev = (i == 0) ? -1 : batch[i-1];
    for (int b = prev+1; b <= cur; ++b) bstart[b] = i;
    if (i == 1999) for (int b = cur+1; b <= 16; ++b) bstart[b] = 2000;
  }
}
__global__ void k_segmax(const float* __restrict__ h, const int* __restrict__ bstart,
                         float* __restrict__ xhead){
  int j = blockIdx.x*256 + threadIdx.x;
  int b = blockIdx.y;
  if (j >= 2000) return;
  int n0 = bstart[b], n1 = bstart[b+1];
  float m = -3.0e38f;
  for (int n = n0; n < n1; ++n) m = fmaxf(m, h[(size_t)n*2000 + j]);
  xhead[(size_t)b*3200 + j] = m;
}

// ---------- token pieces ----------
__global__ void k_embed(const int* __restrict__ tokens, const float* __restrict__ emb,
                        u16* __restrict__ X){
  int k = blockIdx.x*256 + threadIdx.x;
  int row = blockIdx.y;                  // row = t*16+b
  if (k >= 416) return;
  int t = row >> 4, b = row & 15;
  int tok = tokens[b*256 + t];
  float v;
  if (k < 100)                    v = emb[(size_t)tok*100 + k];
  else if (k == 100 || k == 400)  v = 1.f;   // bias-one columns
  else                            v = 0.f;
  X[(size_t)row*416 + k] = f2bf(v);
}
__global__ void k_zeropad(u16* __restrict__ X){
  int r = blockIdx.x*16 + (threadIdx.x >> 4);
  int c = 400 + (threadIdx.x & 15);
  X[(size_t)r*416 + c] = (c == 400) ? (u16)0x3F80 : (u16)0;  // bias-one at 400
}

// Recurrent GRU: 2 WGs (dir), 7 waves each. C[m=gate-output][n=batch].
// A = Whh fragments in registers (rows: g*208+j', col 200 = bhh, rest pad 0).
// B = h from LDS [b][k], k=200 is constant 1.0.
// v2: raw s_barrier (no vmcnt drain), register double-buffer prefetch of gi,
//     v_rcp-based sigmoid/tanh, v_cvt_pk_bf16 packing, direct Xout stores
//     (stage buffer + second barrier removed).
#define RSTEP(GC, GN, GNEXT, S)                                                   \
  {                                                                               \
    _Pragma("unroll")                                                             \
    for (int s_ = 0; s_ < 2; ++s_){                                               \
      if (s_ < ns){                                                               \
        const int jb = (jt0 + s_)*16 + quad*4;                                    \
        GN[s_][0] = *(const uint2*)((GNEXT) + (0*208 + jb));                      \
        GN[s_][1] = *(const uint2*)((GNEXT) + (1*208 + jb));                      \
        GN[s_][2] = *(const uint2*)((GNEXT) + (2*208 + jb));                      \
      }                                                                           \
    }                                                                             \
    const int p_ = (S) & 1;                                                       \
    fx4 acc[2][3];                                                                \
    _Pragma("unroll")                                                             \
    for (int s_ = 0; s_ < 2; ++s_){                                               \
      _Pragma("unroll")                                                           \
      for (int g = 0; g < 3; ++g) acc[s_][g] = fx4{0.f,0.f,0.f,0.f};              \
    }                                                                             \
    const u16* hp = hBs + p_*16*HS + col*HS;                                      \
    _Pragma("unroll")                                                             \
    for (int ks = 0; ks < 7; ++ks){                                               \
      s16x8 bfv = *(const s16x8*)(hp + ks*32 + quad*8);                           \
      _Pragma("unroll")                                                           \
      for (int s_ = 0; s_ < 2; ++s_){                                             \
        if (s_ >= ns) continue;                                                   \
        acc[s_][0] = mfma16(Af[s_][0][ks], bfv, acc[s_][0]);                      \
        acc[s_][1] = mfma16(Af[s_][1][ks], bfv, acc[s_][1]);                      \
        acc[s_][2] = mfma16(Af[s_][2][ks], bfv, acc[s_][2]);                      \
      }                                                                           \
    }                                                                             \
    _Pragma("unroll")                                                             \
    for (int s_ = 0; s_ < 2; ++s_){                                               \
      if (s_ >= ns) continue;                                                     \
      const int jb = (jt0 + s_)*16 + quad*4;                                      \
      _Pragma("unroll")                                                           \
      for (int i = 0; i < 4; ++i){                                                \
        u32 wr = (i < 2) ? GC[s_][0].x : GC[s_][0].y;                             \
        u32 wz = (i < 2) ? GC[s_][1].x : GC[s_][1].y;                             \
        u32 wn = (i < 2) ? GC[s_][2].x : GC[s_][2].y;                             \
        float gr = (i & 1) ? __uint_as_float(wr & 0xffff0000u) : __uint_as_float(wr << 16); \
        float gz = (i & 1) ? __uint_as_float(wz & 0xffff0000u) : __uint_as_float(wz << 16); \
        float gn = (i & 1) ? __uint_as_float(wn & 0xffff0000u) : __uint_as_float(wn << 16); \
        float r  = sigm(gr + acc[s_][0][i]);                                      \
        float z  = sigm(gz + acc[s_][1][i]);                                      \
        float nn = tanh_(fmaf(r, acc[s_][2][i], gn));                             \
        h[s_][i] = nn + z*(h[s_][i] - nn);                                        \
      }                                                                           \
      if (jb < 200){                                                              \
        u32 d0 = cvt_pk_bf16(h[s_][0], h[s_][1]);                                 \
        u32 d1 = cvt_pk_bf16(h[s_][2], h[s_][3]);                                 \
        *(uint2*)(hBs + ((p_^1)*16 + col)*HS + jb) = make_uint2(d0, d1);          \
        if (writeX){                                                              \
          int t_ = dir ? (255 - (S)) : (S);                                       \
          *(uint2*)(Xout + (size_t)(t_*16 + col)*416 + dir*200 + jb) = make_uint2(d0, d1); \
        }                                                                         \
      }                                                                           \
    }                                                                             \
    asm volatile("s_waitcnt lgkmcnt(0)" ::: "memory");                            \
    __builtin_amdgcn_s_barrier();                                                 \
    __builtin_amdgcn_sched_barrier(0);                                            \
  }

__global__ __launch_bounds__(448, 2) void k_recur(
    const u16*  __restrict__ Gt,     // [t][dir][b][624] bf16: r = g*208 + j
    const float* __restrict__ Whh,   // [3][2][600][200]
    const float* __restrict__ bhh,   // [3][2][600]
    u16* __restrict__ Xout,          // [4096][416] bf16
    float* __restrict__ xhead,       // [16][3200]
    int layer, int writeX)
{
  const int dir  = blockIdx.x;
  const int tid  = threadIdx.x;
  const int wv   = tid >> 6, lane = tid & 63;
  const int col  = lane & 15, quad = lane >> 4;
  const int jt0  = wv * 2;               // wave owns j-tiles jt0, jt0+1
  constexpr int HS = 232;
  __shared__ u16 hBs[2*16*HS];
  for (int i = tid; i < 2*16*HS; i += 448) hBs[i] = 0;
  __syncthreads();
  if (tid < 32) hBs[(tid>>4)*16*HS + (tid&15)*HS + 200] = 0x3F80;  // k=200 -> 1.0

  const int ns = (wv == 6) ? 1 : 2;      // wave 6: only tile 12 (j' 192..207)
  s16x8 Af[2][3][7];
  const float* Wb = Whh + (size_t)(layer*2 + dir)*600*200;
  const float* bb = bhh + (size_t)(layer*2 + dir)*600;
#pragma unroll
  for (int s_ = 0; s_ < 2; ++s_){
    if (s_ >= ns) continue;
    int jp = (jt0 + s_)*16 + col;        // A-operand row (m = lane&15)
#pragma unroll
    for (int g = 0; g < 3; ++g)
#pragma unroll
      for (int ks = 0; ks < 7; ++ks){
        s16x8 v;
#pragma unroll
        for (int ii = 0; ii < 8; ++ii){
          int k = ks*32 + quad*8 + ii;
          float w = 0.f;
          if (jp < 200){
            if (k < 200)        w = Wb[(size_t)(g*200 + jp)*200 + k];
            else if (k == 200)  w = bb[g*200 + jp];
          }
          v[ii] = (short)f2bf(w);
        }
        Af[s_][g][ks] = v;
      }
  }
  __syncthreads();

  const int t0 = dir ? 255 : 0;
  const u16* gb = Gt + ((size_t)(t0*2 + dir)*16 + col)*624;
  const ptrdiff_t dstep = dir ? -(ptrdiff_t)19968 : (ptrdiff_t)19968;

  float h[2][4] = {{0.f,0.f,0.f,0.f},{0.f,0.f,0.f,0.f}};
  uint2 g0[2][3], g1[2][3];
  // preload gi for step 0
#pragma unroll
  for (int s_ = 0; s_ < 2; ++s_){
    if (s_ < ns){
      const int jb = (jt0 + s_)*16 + quad*4;
      g0[s_][0] = *(const uint2*)(gb + (0*208 + jb));
      g0[s_][1] = *(const uint2*)(gb + (1*208 + jb));
      g0[s_][2] = *(const uint2*)(gb + (2*208 + jb));
    }
  }

  for (int s = 0; s < 256; s += 2){
    RSTEP(g0, g1, gb + dstep,   s);      // even step: reads buf p=0, writes p=1
    RSTEP(g1, g0, gb + 2*dstep, s+1);    // odd step: reads p=1, writes p=0
    gb += 2*dstep;
  }

#pragma unroll
  for (int s_ = 0; s_ < 2; ++s_){
    if (s_ >= ns) continue;
#pragma unroll
    for (int i = 0; i < 4; ++i){
      int jp = (jt0 + s_)*16 + quad*4 + i;
      if (jp < 200)
        xhead[(size_t)col*3200 + 2000 + (layer*2 + dir)*200 + jp] = h[s_][i];
    }
  }
}

// ---------- head ----------
__global__ void k_head(const float* __restrict__ x, const float* __restrict__ W,
                       const float* __restrict__ bias, float* __restrict__ y,
                       int IN, int OUT){
  int o = blockIdx.x*16 + (threadIdx.x >> 4);
  int b = threadIdx.x & 15;
  if (o >= OUT) return;
  const float* xr = x + (size_t)b*IN;
  const float* wr = W + (size_t)o*IN;
  float s = 0.f;
  for (int k = 0; k < IN; k += 4){
    float4 xv = *(const float4*)(xr + k);
    float4 wv = *(const float4*)(wr + k);
    s += xv.x*wv.x + xv.y*wv.y + xv.z*wv.z + xv.w*wv.w;
  }
  s += bias[o];
  y[(size_t)b*OUT + o] = fmaxf(s, 0.f);
}
__global__ void k_zero_out(float* __restrict__ y, int n){
  int i = blockIdx.x*256 + threadIdx.x;
  if (i < n) y[i] = 0.f;
}

// ---------- workspace layout ----------
constexpr size_t S_WFUSED = (size_t)10112*2048*2;
constexpr size_t S_WIHT   = (size_t)6016*2048*2;
constexpr size_t S_WTOK   = (size_t)3*1280*416*2;
constexpr size_t S_HB     = (size_t)2048*2048*2;
constexpr size_t S_H      = (size_t)2000*2000*4;
constexpr size_t S_HB0    = (size_t)2048*128*2;
constexpr size_t S_C1     = (size_t)2048*10112*4;
constexpr size_t S_C2     = (size_t)2048*6016*4;
constexpr size_t S_X      = (size_t)4096*416*2;

constexpr size_t O_WFUSED = 0;
constexpr size_t O_WIHT   = O_WFUSED + S_WFUSED;
constexpr size_t O_WTOK   = O_WIHT + S_WIHT;
constexpr size_t O_HB     = O_WTOK + S_WTOK;
constexpr size_t O_AB     = O_HB + S_HB;
constexpr size_t O_H      = O_AB + S_HB;
constexpr size_t O_HB0    = O_H + S_H;
constexpr size_t O_C1     = O_HB0 + S_HB0;
constexpr size_t O_C2     = O_C1 + S_C1;
constexpr size_t O_XA     = O_C2 + S_C2;
constexpr size_t O_XB     = O_XA + S_X;
constexpr size_t O_OFFS   = O_XB + S_X;
constexpr size_t O_CUR    = O_OFFS + 2048*4;
constexpr size_t O_EIDX   = O_CUR + 2048*4;
constexpr size_t O_BST    = O_EIDX + 16384*4;
constexpr size_t O_XH     = O_BST + 256;
constexpr size_t O_B1     = O_XH + (size_t)16*3200*4;
constexpr size_t O_B2     = O_B1 + (size_t)16*1024*4;
constexpr size_t WS_NEEDED= O_B2 + (size_t)16*512*4;

extern "C" void kernel_launch(void* const* d_in, const int* in_sizes, int n_in,
                              void* d_out, int out_size, void* d_ws, size_t ws_size,
                              hipStream_t stream)
{
  const float* feats  = (const float*)d_in[0];
  const int*   tokens = (const int*)  d_in[1];
  const int*   esrc   = (const int*)  d_in[2];
  const int*   edst   = (const int*)  d_in[3];
  const int*   eet    = (const int*)  d_in[4];
  const int*   batch  = (const int*)  d_in[5];
  const float* embedw = (const float*)d_in[6];
  const float* gW     = (const float*)d_in[7];
  const float* gb     = (const float*)d_in[8];
  const float* gWih   = (const float*)d_in[9];
  const float* gWhh   = (const float*)d_in[10];
  const float* gbih   = (const float*)d_in[11];
  const float* gbhh   = (const float*)d_in[12];
  const float* tWih   = (const float*)d_in[13];
  const float* tWhh   = (const float*)d_in[14];
  const float* tbih   = (const float*)d_in[15];
  const float* tbhh   = (const float*)d_in[16];
  const float* l1W    = (const float*)d_in[17];
  const float* l1b    = (const float*)d_in[18];
  const float* l11W   = (const float*)d_in[19];
  const float* l11b   = (const float*)d_in[20];
  const float* l2W    = (const float*)d_in[21];
  const float* l2b    = (const float*)d_in[22];
  (void)in_sizes; (void)n_in;

  float* out = (float*)d_out;
  if (ws_size < WS_NEEDED){
    k_zero_out<<<1, 256, 0, stream>>>(out, out_size);
    return;
  }
  uint8_t* ws = (uint8_t*)d_ws;
  u16*   Wfused = (u16*)(ws + O_WFUSED);
  u16*   WihT   = (u16*)(ws + O_WIHT);
  u16*   Wtok   = (u16*)(ws + O_WTOK);
  u16*   HBm    = (u16*)(ws + O_HB);
  u16*   ABm    = (u16*)(ws + O_AB);
  float* Hm     = (float*)(ws + O_H);
  u16*   HB0    = (u16*)(ws + O_HB0);
  float* C1     = (float*)(ws + O_C1);
  float* C2     = (float*)(ws + O_C2);
  u16*   Gt     = (u16*)(ws + O_C2);     // token gi, bf16 scatter layout (reuses C2)
  u16*   XA     = (u16*)(ws + O_XA);
  u16*   XB     = (u16*)(ws + O_XB);
  int*   OFFS   = (int*)(ws + O_OFFS);
  int*   CUR    = (int*)(ws + O_CUR);
  int*   EIDX   = (int*)(ws + O_EIDX);
  int*   BST    = (int*)(ws + O_BST);
  float* XH     = (float*)(ws + O_XH);
  float* B1     = (float*)(ws + O_B1);
  float* B2     = (float*)(ws + O_B2);

  // ---- prep ----
  k_build_wfused<<<dim3(8,10112), 256, 0, stream>>>(gW, gWhh, Wfused);
  k_build_wiht  <<<dim3(8,6016),  256, 0, stream>>>(gWih, WihT);
  k_build_wtok  <<<6240,          256, 0, stream>>>(tWih, tbih, Wtok);
  k_csr1        <<<1,            1024, 0, stream>>>(edst, OFFS, CUR);
  k_csr2        <<<63,            256, 0, stream>>>(esrc, edst, eet, CUR, EIDX);
  k_init_h0     <<<dim3(8,2048),  256, 0, stream>>>(feats, Hm, HB0);
  k_embed       <<<dim3(2,4096),  256, 0, stream>>>(tokens, embedw, XA);
  k_zeropad     <<<256,           256, 0, stream>>>(XB);

  // ---- GGNN: 3 steps ----
  for (int step = 0; step < 3; ++step){
    if (step == 0)
      gemm_bt<0><<<dim3(79,16), 256, 0, stream>>>(HB0, Wfused, C1, 128, 2048, 10112, 128);
    else
      gemm_bt<0><<<dim3(79,16), 256, 0, stream>>>(HBm, Wfused, C1, 2048, 2048, 10112, 2048);
    k_gather<<<dim3(2048,8), 256, 0, stream>>>(C1, OFFS, EIDX, gb, ABm);
    gemm_bt<0><<<dim3(47,16), 256, 0, stream>>>(ABm, WihT, C2, 2048, 2048, 6016, 2048);
    k_gru_elem<<<dim3(8,2048), 256, 0, stream>>>(C1, C2, gbih, gbhh, Hm, HBm);
  }
  k_ranges<<<2, 1024, 0, stream>>>(batch, BST);
  k_segmax<<<dim3(8,16), 256, 0, stream>>>(Hm, BST, XH);

  // ---- token branch: 3 bidirectional GRU layers ----
  gemm_bt<2><<<dim3(10,32), 256, 0, stream>>>(XA, Wtok + 0*(size_t)1280*416, Gt, 416, 416, 0, 128);
  k_recur<<<2, 448, 0, stream>>>(Gt, tWhh, tbhh, XB, XH, 0, 1);
  gemm_bt<2><<<dim3(10,32), 256, 0, stream>>>(XB, Wtok + 1*(size_t)1280*416, Gt, 416, 416, 0, 416);
  k_recur<<<2, 448, 0, stream>>>(Gt, tWhh, tbhh, XA, XH, 1, 1);
  gemm_bt<2><<<dim3(10,32), 256, 0, stream>>>(XA, Wtok + 2*(size_t)1280*416, Gt, 416, 416, 0, 416);
  k_recur<<<2, 448, 0, stream>>>(Gt, tWhh, tbhh, XB, XH, 2, 0);

  // ---- head ----
  k_head<<<63, 256, 0, stream>>>(XH, l1W, l1b, B1, 3200, 1000);
  k_head<<<32, 256, 0, stream>>>(B1, l11W, l11b, B2, 1000, 500);
  k_head<<<1,  256, 0, stream>>>(B2, l2W, l2b, out, 500, 2);
}

// Round 2
// 2863.202 us; speedup vs baseline: 1.2519x; 1.1286x over previous
//
#include <hip/hip_runtime.h>
#include <cstdint>
#include <cstddef>

typedef unsigned short u16;
typedef unsigned int   u32;
typedef __attribute__((ext_vector_type(8))) short s16x8;
typedef __attribute__((ext_vector_type(4))) float fx4;

// ---------- helpers ----------
__device__ __forceinline__ u16 f2bf(float x){
  u32 u = __float_as_uint(x);
  u32 r = (u + 0x7fffu + ((u >> 16) & 1u)) >> 16;   // RNE
  return (u16)r;
}
__device__ __forceinline__ float bf2f(u16 x){
  return __uint_as_float(((u32)x) << 16);
}
__device__ __forceinline__ float rcp_(float x){ return __builtin_amdgcn_rcpf(x); }
__device__ __forceinline__ float exp2_(float x){
  float r; asm("v_exp_f32 %0, %1" : "=v"(r) : "v"(x)); return r;
}
__device__ __forceinline__ float sigm(float x){ return rcp_(1.f + __expf(-x)); }
__device__ __forceinline__ float tanh_(float x){
  x = fminf(fmaxf(x, -15.f), 15.f);
  float e = __expf(2.f*x);
  return (e-1.f)*rcp_(e+1.f);
}
__device__ __forceinline__ u32 cvt_pk_bf16(float lo, float hi){
  u32 d;
  asm("v_cvt_pk_bf16_f32 %0, %1, %2" : "=v"(d) : "v"(lo), "v"(hi));
  return d;
}
__device__ __forceinline__ void gl_lds16(const u16* g, u16* l){
  __builtin_amdgcn_global_load_lds((__attribute__((address_space(1))) void*)(void*)g,
                                   (__attribute__((address_space(3))) void*)(void*)l,
                                   16, 0, 0);
}
__device__ __forceinline__ fx4 mfma16(s16x8 a, s16x8 b, fx4 c){
  return __builtin_amdgcn_mfma_f32_16x16x32_bf16(a, b, c, 0, 0, 0);
}

// gate prescale: r,z rows by -log2(e); n rows by 2*log2(e)  (exp2-domain gates)
#define GSC_RZ (-1.442695041f)
#define GSC_N  ( 2.885390082f)

// ---------- generic bf16 GEMM  C[M][N] = A[M][K] * Bt[N][K]^T  (m97 structure) ----------
// MODE 0: fp32 row-major C.  MODE 2: bf16 scatter into Gt[t][dir][b][624] token layout.
template<int MODE>
__global__ __launch_bounds__(256, 2) void gemm_bt(
    const u16* __restrict__ A, const u16* __restrict__ Bt, void* __restrict__ Cp,
    int lda, int ldb, int ldc, int K)
{
  __shared__ u16 As[128*32];
  __shared__ u16 Bs[128*32];
  const int t    = threadIdx.x;
  const int lane = t & 63;
  const int wave = t >> 6;
  const int mw   = (wave >> 1) * 64;
  const int nw   = (wave & 1) * 64;
  const int m0   = blockIdx.y * 128;
  const int n0   = blockIdx.x * 128;
  const int col  = lane & 15, quad = lane >> 4;

  fx4 acc[4][4];
#pragma unroll
  for (int i=0;i<4;i++)
#pragma unroll
    for (int j=0;j<4;j++) acc[i][j] = fx4{0.f,0.f,0.f,0.f};

  const int u0 = t, u1 = t + 256;
  const int ar0 = u0 >> 2, ac0 = (u0 & 3) * 8;
  const int ar1 = u1 >> 2, ac1 = (u1 & 3) * 8;
  const u16* gA0 = A  + (size_t)(m0 + ar0) * lda + ac0;
  const u16* gA1 = A  + (size_t)(m0 + ar1) * lda + ac1;
  const u16* gB0 = Bt + (size_t)(n0 + ar0) * ldb + ac0;
  const u16* gB1 = Bt + (size_t)(n0 + ar1) * ldb + ac1;
  u16* lA0 = As + u0*8; u16* lA1 = As + u1*8;
  u16* lB0 = Bs + u0*8; u16* lB1 = Bs + u1*8;
  const u16* pa = As + (mw + col)*32 + quad*8;
  const u16* pb = Bs + (nw + col)*32 + quad*8;

  for (int k0 = 0; k0 < K; k0 += 32){
    gl_lds16(gA0 + k0, lA0);
    gl_lds16(gA1 + k0, lA1);
    gl_lds16(gB0 + k0, lB0);
    gl_lds16(gB1 + k0, lB1);
    __syncthreads();
    s16x8 af[4], bf[4];
#pragma unroll
    for (int mt=0; mt<4; ++mt) af[mt] = *(const s16x8*)(pa + mt*512);
#pragma unroll
    for (int nt=0; nt<4; ++nt) bf[nt] = *(const s16x8*)(pb + nt*512);
#pragma unroll
    for (int mt=0; mt<4; ++mt)
#pragma unroll
      for (int nt=0; nt<4; ++nt)
        acc[mt][nt] = mfma16(af[mt], bf[nt], acc[mt][nt]);
    __syncthreads();
  }
#pragma unroll
  for (int mt=0; mt<4; ++mt)
#pragma unroll
    for (int nt=0; nt<4; ++nt)
#pragma unroll
      for (int i=0; i<4; ++i){
        int m = m0 + mw + mt*16 + quad*4 + i;
        int n = n0 + nw + nt*16 + col;
        float v = acc[mt][nt][i];
        if (MODE == 0){
          ((float*)Cp)[(size_t)m*ldc + n] = v;
        } else {
          if (n < 1248){
            int dir = (n >= 624) ? 1 : 0;
            int r   = n - dir*624;
            int tt  = m >> 4, b = m & 15;
            ((u16*)Cp)[((size_t)((tt*2 + dir)*16 + b))*624 + r] = f2bf(v);
          }
        }
      }
}

// ---------- weight prep ----------
__global__ void k_build_wfused(const float* __restrict__ gW, const float* __restrict__ gWhh,
                               u16* __restrict__ out){
  int k = blockIdx.x*256 + threadIdx.x;   // 0..2047
  int n = blockIdx.y;                     // 0..10111
  float v = 0.f;
  if (k < 2000){
    if (n < 4000)       v = gW  [(size_t)n*2000 + k];
    else if (n < 10000) v = gWhh[(size_t)(n-4000)*2000 + k];
  }
  out[(size_t)n*2048 + k] = f2bf(v);
}
__global__ void k_build_wiht(const float* __restrict__ W, u16* __restrict__ out){
  int k = blockIdx.x*256 + threadIdx.x;
  int n = blockIdx.y;                     // 0..6015
  float v = (k < 2000 && n < 6000) ? W[(size_t)n*2000 + k] : 0.f;
  out[(size_t)n*2048 + k] = f2bf(v);
}
// token Wih; columns n = dir*624 + g*208 + j (j<200 real). bih folded at
// input col 100 (layer0) / 400 (layers 1,2). Rows prescaled for exp2 gates.
__global__ void k_build_wtok(const float* __restrict__ gw, const float* __restrict__ bih,
                             u16* __restrict__ out){
  size_t idx = (size_t)blockIdx.x*256 + threadIdx.x;
  if (idx >= (size_t)3*1280*416) return;
  int k = (int)(idx % 416);
  int n = (int)((idx/416) % 1280);
  int l = (int)(idx/(416*1280));
  float v = 0.f;
  int dir = -1, r = 0;
  if (n < 624){ dir = 0; r = n; }
  else if (n < 1248){ dir = 1; r = n - 624; }
  if (dir >= 0){
    int g = r / 208, j = r % 208;
    if (j < 200){
      int row = (l*2 + dir)*600 + g*200 + j;
      int kreal = (l == 0) ? 100 : 400;
      if (k < kreal)       v = gw[(size_t)row*400 + k];
      else if (k == kreal) v = bih[row];
      v *= (g == 2) ? GSC_N : GSC_RZ;
    }
  }
  out[idx] = f2bf(v);
}

// ---------- CSR ----------
__global__ void k_csr1(const int* __restrict__ dst, int* __restrict__ offs,
                       int* __restrict__ cursor){
  __shared__ int c0[2048];
  __shared__ int c1[2048];
  int tid = threadIdx.x; // 1024
  c0[tid] = 0; c0[tid+1024] = 0;
  __syncthreads();
  for (int e = tid; e < 16000; e += 1024) atomicAdd(&c0[dst[e]], 1);
  __syncthreads();
  int* s = c0; int* d = c1;
  for (int off = 1; off < 2048; off <<= 1){
    for (int i = tid; i < 2048; i += 1024){
      int v = s[i];
      if (i >= off) v += s[i-off];
      d[i] = v;
    }
    __syncthreads();
    int* tmp = s; s = d; d = tmp;
  }
  for (int i = tid; i < 2048; i += 1024){
    int ex = (i == 0) ? 0 : s[i-1];
    if (i <= 2000) offs[i] = ex;
    if (i < 2000)  cursor[i] = ex;
  }
}
__global__ void k_csr2(const int* __restrict__ src, const int* __restrict__ dst,
                       const int* __restrict__ et, int* __restrict__ cursor,
                       int* __restrict__ eidx){
  int e = blockIdx.x*256 + threadIdx.x;
  if (e >= 16000) return;
  int pos = atomicAdd(&cursor[dst[e]], 1);
  eidx[pos] = (src[e] << 1) | (et[e] & 1);
}

// ---------- GGNN pieces ----------
__global__ void k_init_h0(const float* __restrict__ feats, float* __restrict__ h,
                          u16* __restrict__ hb0){
  int j = blockIdx.x*256 + threadIdx.x;  // 0..2047
  int m = blockIdx.y;                    // 0..2047
  float v = (m < 2000 && j < 100) ? feats[(size_t)m*100 + j] : 0.f;
  if (m < 2000 && j < 2000) h[(size_t)m*2000 + j] = v;
  if (j < 128) hb0[(size_t)m*128 + j] = f2bf(v);
}
__global__ void k_gather(const float* __restrict__ C1, const int* __restrict__ offs,
                         const int* __restrict__ eidx, const float* __restrict__ gb,
                         u16* __restrict__ ab){
  int c = blockIdx.y*256 + threadIdx.x;  // 0..2047
  int n = blockIdx.x;                    // 0..2047
  float s = 0.f;
  if (n < 2000 && c < 2000){
    int p0 = offs[n], p1 = offs[n+1];
    for (int p = p0; p < p1; ++p){
      int pk = eidx[p];
      int sn = pk >> 1, e = pk & 1;
      s += C1[(size_t)sn*10112 + e*2000 + c] + gb[(size_t)e*2000 + c];
    }
  }
  ab[(size_t)n*2048 + c] = f2bf(s);
}
__global__ void k_gru_elem(const float* __restrict__ C1, const float* __restrict__ C2,
                           const float* __restrict__ bih, const float* __restrict__ bhh,
                           float* __restrict__ h, u16* __restrict__ hb){
  int j = blockIdx.x*256 + threadIdx.x;  // 0..2047
  int m = blockIdx.y;                    // 0..2047
  float hv = 0.f;
  if (m < 2000 && j < 2000){
    const float* c1 = C1 + (size_t)m*10112;
    const float* c2 = C2 + (size_t)m*6016;
    float gir = c2[j]        + bih[j];
    float giz = c2[2000 + j] + bih[2000 + j];
    float gin = c2[4000 + j] + bih[4000 + j];
    float ghr = c1[4000 + j] + bhh[j];
    float ghz = c1[6000 + j] + bhh[2000 + j];
    float ghn = c1[8000 + j] + bhh[4000 + j];
    float r  = sigm(gir + ghr);
    float z  = sigm(giz + ghz);
    float nn = tanh_(gin + r*ghn);
    float ho = h[(size_t)m*2000 + j];
    hv = (1.f - z)*nn + z*ho;
    h[(size_t)m*2000 + j] = hv;
  }
  hb[(size_t)m*2048 + j] = f2bf(hv);
}
__global__ void k_ranges(const int* __restrict__ batch, int* __restrict__ bstart){
  int i = blockIdx.x*1024 + threadIdx.x;
  if (i < 2000){
    int cur  = batch[i];
    int prev = (i == 0) ? -1 : batch[i-1];
    for (int b = prev+1; b <= cur; ++b) bstart[b] = i;
    if (i == 1999) for (int b = cur+1; b <= 16; ++b) bstart[b] = 2000;
  }
}
__global__ void k_segmax(const float* __restrict__ h, const int* __restrict__ bstart,
                         float* __restrict__ xhead){
  int j = blockIdx.x*256 + threadIdx.x;
  int b = blockIdx.y;
  if (j >= 2000) return;
  int n0 = bstart[b], n1 = bstart[b+1];
  float m = -3.0e38f;
  for (int n = n0; n < n1; ++n) m = fmaxf(m, h[(size_t)n*2000 + j]);
  xhead[(size_t)b*3200 + j] = m;
}

// ---------- token pieces ----------
__global__ void k_embed(const int* __restrict__ tokens, const float* __restrict__ emb,
                        u16* __restrict__ X){
  int k = blockIdx.x*256 + threadIdx.x;
  int row = blockIdx.y;                  // row = t*16+b
  if (k >= 416) return;
  int t = row >> 4, b = row & 15;
  int tok = tokens[b*256 + t];
  float v;
  if (k < 100)                    v = emb[(size_t)tok*100 + k];
  else if (k == 100 || k == 400)  v = 1.f;   // bias-one columns
  else                            v = 0.f;
  X[(size_t)row*416 + k] = f2bf(v);
}
__global__ void k_zeropad(u16* __restrict__ X){
  int r = blockIdx.x*16 + (threadIdx.x >> 4);
  int c = 400 + (threadIdx.x & 15);
  X[(size_t)r*416 + c] = (c == 400) ? (u16)0x3F80 : (u16)0;  // bias-one at 400
}

// Recurrent GRU: 2 WGs (dir), 13 waves each, 1 j-tile per wave (uniform work,
// no barrier skew, 4/3/3/3 waves per SIMD). C[m=gate-output j][n=batch].
// A = Whh fragments in registers (prescaled to exp2 domain; col 200 = bhh).
// B = h from LDS [b][k], k=200 is constant 1.0.
// Per step: prefetch next gi; acc init = gi (r,z); split-K MFMA chains;
// exp2-domain gates; ds_write next h; raw barrier (no vmcnt drain).
#define RSTEP(GC, GN, GNEXT, S)                                                   \
  {                                                                               \
    GN[0] = *(const uint2*)((GNEXT) + (0*208 + jb));                              \
    GN[1] = *(const uint2*)((GNEXT) + (1*208 + jb));                              \
    GN[2] = *(const uint2*)((GNEXT) + (2*208 + jb));                              \
    const int p_ = (S) & 1;                                                       \
    float giR[4], giZ[4], giN[4];                                                 \
    _Pragma("unroll")                                                             \
    for (int i = 0; i < 4; ++i){                                                  \
      u32 wr = (i < 2) ? GC[0].x : GC[0].y;                                       \
      u32 wz = (i < 2) ? GC[1].x : GC[1].y;                                       \
      u32 wn = (i < 2) ? GC[2].x : GC[2].y;                                       \
      giR[i] = (i & 1) ? __uint_as_float(wr & 0xffff0000u) : __uint_as_float(wr << 16); \
      giZ[i] = (i & 1) ? __uint_as_float(wz & 0xffff0000u) : __uint_as_float(wz << 16); \
      giN[i] = (i & 1) ? __uint_as_float(wn & 0xffff0000u) : __uint_as_float(wn << 16); \
    }                                                                             \
    fx4 aR  = fx4{giR[0], giR[1], giR[2], giR[3]};                                \
    fx4 aZ  = fx4{giZ[0], giZ[1], giZ[2], giZ[3]};                                \
    fx4 aR1 = fx4{0.f,0.f,0.f,0.f}, aZ1 = fx4{0.f,0.f,0.f,0.f};                   \
    fx4 aN  = fx4{0.f,0.f,0.f,0.f}, aN1 = fx4{0.f,0.f,0.f,0.f};                   \
    const u16* hp = hBs + p_*16*HS + col*HS;                                      \
    _Pragma("unroll")                                                             \
    for (int ks = 0; ks < 7; ++ks){                                               \
      s16x8 bv = *(const s16x8*)(hp + ks*32 + quad*8);                            \
      if (ks & 1){                                                                \
        aR1 = mfma16(Af[0][ks], bv, aR1);                                         \
        aZ1 = mfma16(Af[1][ks], bv, aZ1);                                         \
        aN1 = mfma16(Af[2][ks], bv, aN1);                                         \
      } else {                                                                    \
        aR  = mfma16(Af[0][ks], bv, aR );                                         \
        aZ  = mfma16(Af[1][ks], bv, aZ );                                         \
        aN  = mfma16(Af[2][ks], bv, aN );                                         \
      }                                                                           \
    }                                                                             \
    aR += aR1; aZ += aZ1; aN += aN1;                                              \
    _Pragma("unroll")                                                             \
    for (int i = 0; i < 4; ++i){                                                  \
      float r = rcp_(1.f + exp2_(aR[i]));                                         \
      float z = rcp_(1.f + exp2_(aZ[i]));                                         \
      float x = fmaf(r, aN[i], giN[i]);                                           \
      x = fminf(x, 100.f);                                                        \
      float e = exp2_(x);                                                         \
      float nn = (e - 1.f)*rcp_(e + 1.f);                                         \
      h[i] = nn + z*(h[i] - nn);                                                  \
    }                                                                             \
    if (jb < 200){                                                                \
      u32 d0 = cvt_pk_bf16(h[0], h[1]);                                           \
      u32 d1 = cvt_pk_bf16(h[2], h[3]);                                           \
      *(uint2*)(hBs + ((p_^1)*16 + col)*HS + jb) = make_uint2(d0, d1);            \
      if (writeX){                                                                \
        int t_ = dir ? (255 - (S)) : (S);                                         \
        *(uint2*)(Xout + (size_t)(t_*16 + col)*416 + dir*200 + jb) = make_uint2(d0, d1); \
      }                                                                           \
    }                                                                             \
    asm volatile("s_waitcnt lgkmcnt(0)" ::: "memory");                            \
    __builtin_amdgcn_s_barrier();                                                 \
    __builtin_amdgcn_sched_barrier(0);                                            \
  }

__global__ __launch_bounds__(832, 1) void k_recur(
    const u16*  __restrict__ Gt,     // [t][dir][b][624] bf16: r = g*208 + j (prescaled)
    const float* __restrict__ Whh,   // [3][2][600][200]
    const float* __restrict__ bhh,   // [3][2][600]
    u16* __restrict__ Xout,          // [4096][416] bf16
    float* __restrict__ xhead,       // [16][3200]
    int layer, int writeX)
{
  const int dir  = blockIdx.x;
  const int tid  = threadIdx.x;
  const int wv   = tid >> 6, lane = tid & 63;
  const int col  = lane & 15, quad = lane >> 4;
  constexpr int HS = 232;
  __shared__ u16 hBs[2*16*HS];
  for (int i = tid; i < 2*16*HS; i += 832) hBs[i] = 0;
  __syncthreads();
  if (tid < 32) hBs[(tid>>4)*16*HS + (tid&15)*HS + 200] = 0x3F80;  // k=200 -> 1.0

  const int jp = wv*16 + col;            // A-operand row (gate-output index)
  const int jb = wv*16 + quad*4;         // this lane's 4 h outputs
  s16x8 Af[3][7];
  const float* Wb = Whh + (size_t)(layer*2 + dir)*600*200;
  const float* bb = bhh + (size_t)(layer*2 + dir)*600;
#pragma unroll
  for (int g = 0; g < 3; ++g){
    const float gsc = (g == 2) ? GSC_N : GSC_RZ;
#pragma unroll
    for (int ks = 0; ks < 7; ++ks){
      s16x8 v;
#pragma unroll
      for (int ii = 0; ii < 8; ++ii){
        int k = ks*32 + quad*8 + ii;
        float w = 0.f;
        if (jp < 200){
          if (k < 200)        w = Wb[(size_t)(g*200 + jp)*200 + k];
          else if (k == 200)  w = bb[g*200 + jp];
        }
        v[ii] = (short)f2bf(w * gsc);
      }
      Af[g][ks] = v;
    }
  }
  __syncthreads();

  const int t0 = dir ? 255 : 0;
  const u16* gb = Gt + ((size_t)(t0*2 + dir)*16 + col)*624;
  const ptrdiff_t dstep = dir ? -(ptrdiff_t)19968 : (ptrdiff_t)19968;

  float h[4] = {0.f,0.f,0.f,0.f};
  uint2 g0[3], g1[3];
  // preload gi for step 0
  g0[0] = *(const uint2*)(gb + (0*208 + jb));
  g0[1] = *(const uint2*)(gb + (1*208 + jb));
  g0[2] = *(const uint2*)(gb + (2*208 + jb));

  for (int s = 0; s < 256; s += 2){
    RSTEP(g0, g1, gb + dstep,   s);      // even step: reads buf p=0, writes p=1
    RSTEP(g1, g0, gb + 2*dstep, s+1);    // odd step: reads p=1, writes p=0
    gb += 2*dstep;
  }

#pragma unroll
  for (int i = 0; i < 4; ++i){
    int j = jb + i;
    if (j < 200)
      xhead[(size_t)col*3200 + 2000 + (layer*2 + dir)*200 + j] = h[i];
  }
}

// ---------- head ----------
__global__ void k_head(const float* __restrict__ x, const float* __restrict__ W,
                       const float* __restrict__ bias, float* __restrict__ y,
                       int IN, int OUT){
  int o = blockIdx.x*16 + (threadIdx.x >> 4);
  int b = threadIdx.x & 15;
  if (o >= OUT) return;
  const float* xr = x + (size_t)b*IN;
  const float* wr = W + (size_t)o*IN;
  float s = 0.f;
  for (int k = 0; k < IN; k += 4){
    float4 xv = *(const float4*)(xr + k);
    float4 wv = *(const float4*)(wr + k);
    s += xv.x*wv.x + xv.y*wv.y + xv.z*wv.z + xv.w*wv.w;
  }
  s += bias[o];
  y[(size_t)b*OUT + o] = fmaxf(s, 0.f);
}
__global__ void k_zero_out(float* __restrict__ y, int n){
  int i = blockIdx.x*256 + threadIdx.x;
  if (i < n) y[i] = 0.f;
}

// ---------- workspace layout ----------
constexpr size_t S_WFUSED = (size_t)10112*2048*2;
constexpr size_t S_WIHT   = (size_t)6016*2048*2;
constexpr size_t S_WTOK   = (size_t)3*1280*416*2;
constexpr size_t S_HB     = (size_t)2048*2048*2;
constexpr size_t S_H      = (size_t)2000*2000*4;
constexpr size_t S_HB0    = (size_t)2048*128*2;
constexpr size_t S_C1     = (size_t)2048*10112*4;
constexpr size_t S_C2     = (size_t)2048*6016*4;
constexpr size_t S_X      = (size_t)4096*416*2;

constexpr size_t O_WFUSED = 0;
constexpr size_t O_WIHT   = O_WFUSED + S_WFUSED;
constexpr size_t O_WTOK   = O_WIHT + S_WIHT;
constexpr size_t O_HB     = O_WTOK + S_WTOK;
constexpr size_t O_AB     = O_HB + S_HB;
constexpr size_t O_H      = O_AB + S_HB;
constexpr size_t O_HB0    = O_H + S_H;
constexpr size_t O_C1     = O_HB0 + S_HB0;
constexpr size_t O_C2     = O_C1 + S_C1;
constexpr size_t O_XA     = O_C2 + S_C2;
constexpr size_t O_XB     = O_XA + S_X;
constexpr size_t O_OFFS   = O_XB + S_X;
constexpr size_t O_CUR    = O_OFFS + 2048*4;
constexpr size_t O_EIDX   = O_CUR + 2048*4;
constexpr size_t O_BST    = O_EIDX + 16384*4;
constexpr size_t O_XH     = O_BST + 256;
constexpr size_t O_B1     = O_XH + (size_t)16*3200*4;
constexpr size_t O_B2     = O_B1 + (size_t)16*1024*4;
constexpr size_t WS_NEEDED= O_B2 + (size_t)16*512*4;

extern "C" void kernel_launch(void* const* d_in, const int* in_sizes, int n_in,
                              void* d_out, int out_size, void* d_ws, size_t ws_size,
                              hipStream_t stream)
{
  const float* feats  = (const float*)d_in[0];
  const int*   tokens = (const int*)  d_in[1];
  const int*   esrc   = (const int*)  d_in[2];
  const int*   edst   = (const int*)  d_in[3];
  const int*   eet    = (const int*)  d_in[4];
  const int*   batch  = (const int*)  d_in[5];
  const float* embedw = (const float*)d_in[6];
  const float* gW     = (const float*)d_in[7];
  const float* gb     = (const float*)d_in[8];
  const float* gWih   = (const float*)d_in[9];
  const float* gWhh   = (const float*)d_in[10];
  const float* gbih   = (const float*)d_in[11];
  const float* gbhh   = (const float*)d_in[12];
  const float* tWih   = (const float*)d_in[13];
  const float* tWhh   = (const float*)d_in[14];
  const float* tbih   = (const float*)d_in[15];
  const float* tbhh   = (const float*)d_in[16];
  const float* l1W    = (const float*)d_in[17];
  const float* l1b    = (const float*)d_in[18];
  const float* l11W   = (const float*)d_in[19];
  const float* l11b   = (const float*)d_in[20];
  const float* l2W    = (const float*)d_in[21];
  const float* l2b    = (const float*)d_in[22];
  (void)in_sizes; (void)n_in;

  float* out = (float*)d_out;
  if (ws_size < WS_NEEDED){
    k_zero_out<<<1, 256, 0, stream>>>(out, out_size);
    return;
  }
  uint8_t* ws = (uint8_t*)d_ws;
  u16*   Wfused = (u16*)(ws + O_WFUSED);
  u16*   WihT   = (u16*)(ws + O_WIHT);
  u16*   Wtok   = (u16*)(ws + O_WTOK);
  u16*   HBm    = (u16*)(ws + O_HB);
  u16*   ABm    = (u16*)(ws + O_AB);
  float* Hm     = (float*)(ws + O_H);
  u16*   HB0    = (u16*)(ws + O_HB0);
  float* C1     = (float*)(ws + O_C1);
  float* C2     = (float*)(ws + O_C2);
  u16*   Gt     = (u16*)(ws + O_C2);     // token gi, bf16 scatter layout (reuses C2)
  u16*   XA     = (u16*)(ws + O_XA);
  u16*   XB     = (u16*)(ws + O_XB);
  int*   OFFS   = (int*)(ws + O_OFFS);
  int*   CUR    = (int*)(ws + O_CUR);
  int*   EIDX   = (int*)(ws + O_EIDX);
  int*   BST    = (int*)(ws + O_BST);
  float* XH     = (float*)(ws + O_XH);
  float* B1     = (float*)(ws + O_B1);
  float* B2     = (float*)(ws + O_B2);

  // ---- prep ----
  k_build_wfused<<<dim3(8,10112), 256, 0, stream>>>(gW, gWhh, Wfused);
  k_build_wiht  <<<dim3(8,6016),  256, 0, stream>>>(gWih, WihT);
  k_build_wtok  <<<6240,          256, 0, stream>>>(tWih, tbih, Wtok);
  k_csr1        <<<1,            1024, 0, stream>>>(edst, OFFS, CUR);
  k_csr2        <<<63,            256, 0, stream>>>(esrc, edst, eet, CUR, EIDX);
  k_init_h0     <<<dim3(8,2048),  256, 0, stream>>>(feats, Hm, HB0);
  k_embed       <<<dim3(2,4096),  256, 0, stream>>>(tokens, embedw, XA);
  k_zeropad     <<<256,           256, 0, stream>>>(XB);

  // ---- GGNN: 3 steps ----
  for (int step = 0; step < 3; ++step){
    if (step == 0)
      gemm_bt<0><<<dim3(79,16), 256, 0, stream>>>(HB0, Wfused, C1, 128, 2048, 10112, 128);
    else
      gemm_bt<0><<<dim3(79,16), 256, 0, stream>>>(HBm, Wfused, C1, 2048, 2048, 10112, 2048);
    k_gather<<<dim3(2048,8), 256, 0, stream>>>(C1, OFFS, EIDX, gb, ABm);
    gemm_bt<0><<<dim3(47,16), 256, 0, stream>>>(ABm, WihT, C2, 2048, 2048, 6016, 2048);
    k_gru_elem<<<dim3(8,2048), 256, 0, stream>>>(C1, C2, gbih, gbhh, Hm, HBm);
  }
  k_ranges<<<2, 1024, 0, stream>>>(batch, BST);
  k_segmax<<<dim3(8,16), 256, 0, stream>>>(Hm, BST, XH);

  // ---- token branch: 3 bidirectional GRU layers ----
  gemm_bt<2><<<dim3(10,32), 256, 0, stream>>>(XA, Wtok + 0*(size_t)1280*416, Gt, 416, 416, 0, 128);
  k_recur<<<2, 832, 0, stream>>>(Gt, tWhh, tbhh, XB, XH, 0, 1);
  gemm_bt<2><<<dim3(10,32), 256, 0, stream>>>(XB, Wtok + 1*(size_t)1280*416, Gt, 416, 416, 0, 416);
  k_recur<<<2, 832, 0, stream>>>(Gt, tWhh, tbhh, XA, XH, 1, 1);
  gemm_bt<2><<<dim3(10,32), 256, 0, stream>>>(XA, Wtok + 2*(size_t)1280*416, Gt, 416, 416, 0, 416);
  k_recur<<<2, 832, 0, stream>>>(Gt, tWhh, tbhh, XB, XH, 2, 0);

  // ---- head ----
  k_head<<<63, 256, 0, stream>>>(XH, l1W, l1b, B1, 3200, 1000);
  k_head<<<32, 256, 0, stream>>>(B1, l11W, l11b, B2, 1000, 500);
  k_head<<<1,  256, 0, stream>>>(B2, l2W, l2b, out, 500, 2);
}

// Round 3
// 2690.227 us; speedup vs baseline: 1.3324x; 1.0643x over previous
//
#include <hip/hip_runtime.h>
#include <cstdint>
#include <cstddef>

typedef unsigned short u16;
typedef unsigned int   u32;
typedef __attribute__((ext_vector_type(8))) short s16x8;
typedef __attribute__((ext_vector_type(4))) float fx4;

// ---------- helpers ----------
__device__ __forceinline__ u16 f2bf(float x){
  u32 u = __float_as_uint(x);
  u32 r = (u + 0x7fffu + ((u >> 16) & 1u)) >> 16;   // RNE
  return (u16)r;
}
__device__ __forceinline__ float bf2f(u16 x){
  return __uint_as_float(((u32)x) << 16);
}
__device__ __forceinline__ float rcp_(float x){ return __builtin_amdgcn_rcpf(x); }
__device__ __forceinline__ float exp2_(float x){
  float r; asm("v_exp_f32 %0, %1" : "=v"(r) : "v"(x)); return r;
}
__device__ __forceinline__ float sigm(float x){ return rcp_(1.f + __expf(-x)); }
__device__ __forceinline__ float tanh_(float x){
  x = fminf(fmaxf(x, -15.f), 15.f);
  float e = __expf(2.f*x);
  return (e-1.f)*rcp_(e+1.f);
}
__device__ __forceinline__ u32 cvt_pk_bf16(float lo, float hi){
  u32 d;
  asm("v_cvt_pk_bf16_f32 %0, %1, %2" : "=v"(d) : "v"(lo), "v"(hi));
  return d;
}
__device__ __forceinline__ void gl_lds16(const u16* g, u16* l){
  __builtin_amdgcn_global_load_lds((__attribute__((address_space(1))) void*)(void*)g,
                                   (__attribute__((address_space(3))) void*)(void*)l,
                                   16, 0, 0);
}
__device__ __forceinline__ fx4 mfma16(s16x8 a, s16x8 b, fx4 c){
  return __builtin_amdgcn_mfma_f32_16x16x32_bf16(a, b, c, 0, 0, 0);
}

// gate prescale: r,z rows by -log2(e); n rows by 2*log2(e)  (exp2-domain gates)
#define GSC_RZ (-1.442695041f)
#define GSC_N  ( 2.885390082f)

// ---------- generic bf16 GEMM  C[M][N] = A[M][K] * Bt[N][K]^T  (m97 structure) ----------
// MODE 0: fp32 row-major C.  MODE 2: fp32 scatter into Gt[t][dir][b][624] token layout.
template<int MODE>
__global__ __launch_bounds__(256, 2) void gemm_bt(
    const u16* __restrict__ A, const u16* __restrict__ Bt, void* __restrict__ Cp,
    int lda, int ldb, int ldc, int K)
{
  __shared__ u16 As[128*32];
  __shared__ u16 Bs[128*32];
  const int t    = threadIdx.x;
  const int lane = t & 63;
  const int wave = t >> 6;
  const int mw   = (wave >> 1) * 64;
  const int nw   = (wave & 1) * 64;
  const int m0   = blockIdx.y * 128;
  const int n0   = blockIdx.x * 128;
  const int col  = lane & 15, quad = lane >> 4;

  fx4 acc[4][4];
#pragma unroll
  for (int i=0;i<4;i++)
#pragma unroll
    for (int j=0;j<4;j++) acc[i][j] = fx4{0.f,0.f,0.f,0.f};

  const int u0 = t, u1 = t + 256;
  const int ar0 = u0 >> 2, ac0 = (u0 & 3) * 8;
  const int ar1 = u1 >> 2, ac1 = (u1 & 3) * 8;
  const u16* gA0 = A  + (size_t)(m0 + ar0) * lda + ac0;
  const u16* gA1 = A  + (size_t)(m0 + ar1) * lda + ac1;
  const u16* gB0 = Bt + (size_t)(n0 + ar0) * ldb + ac0;
  const u16* gB1 = Bt + (size_t)(n0 + ar1) * ldb + ac1;
  u16* lA0 = As + u0*8; u16* lA1 = As + u1*8;
  u16* lB0 = Bs + u0*8; u16* lB1 = Bs + u1*8;
  const u16* pa = As + (mw + col)*32 + quad*8;
  const u16* pb = Bs + (nw + col)*32 + quad*8;

  for (int k0 = 0; k0 < K; k0 += 32){
    gl_lds16(gA0 + k0, lA0);
    gl_lds16(gA1 + k0, lA1);
    gl_lds16(gB0 + k0, lB0);
    gl_lds16(gB1 + k0, lB1);
    __syncthreads();
    s16x8 af[4], bf[4];
#pragma unroll
    for (int mt=0; mt<4; ++mt) af[mt] = *(const s16x8*)(pa + mt*512);
#pragma unroll
    for (int nt=0; nt<4; ++nt) bf[nt] = *(const s16x8*)(pb + nt*512);
#pragma unroll
    for (int mt=0; mt<4; ++mt)
#pragma unroll
      for (int nt=0; nt<4; ++nt)
        acc[mt][nt] = mfma16(af[mt], bf[nt], acc[mt][nt]);
    __syncthreads();
  }
#pragma unroll
  for (int mt=0; mt<4; ++mt)
#pragma unroll
    for (int nt=0; nt<4; ++nt)
#pragma unroll
      for (int i=0; i<4; ++i){
        int m = m0 + mw + mt*16 + quad*4 + i;
        int n = n0 + nw + nt*16 + col;
        float v = acc[mt][nt][i];
        if (MODE == 0){
          ((float*)Cp)[(size_t)m*ldc + n] = v;
        } else {
          if (n < 1248){
            int dir = (n >= 624) ? 1 : 0;
            int r   = n - dir*624;
            int tt  = m >> 4, b = m & 15;
            ((float*)Cp)[((size_t)((tt*2 + dir)*16 + b))*624 + r] = v;
          }
        }
      }
}

// ---------- weight prep ----------
__global__ void k_build_wfused(const float* __restrict__ gW, const float* __restrict__ gWhh,
                               u16* __restrict__ out){
  int k = blockIdx.x*256 + threadIdx.x;   // 0..2047
  int n = blockIdx.y;                     // 0..10111
  float v = 0.f;
  if (k < 2000){
    if (n < 4000)       v = gW  [(size_t)n*2000 + k];
    else if (n < 10000) v = gWhh[(size_t)(n-4000)*2000 + k];
  }
  out[(size_t)n*2048 + k] = f2bf(v);
}
__global__ void k_build_wiht(const float* __restrict__ W, u16* __restrict__ out){
  int k = blockIdx.x*256 + threadIdx.x;
  int n = blockIdx.y;                     // 0..6015
  float v = (k < 2000 && n < 6000) ? W[(size_t)n*2000 + k] : 0.f;
  out[(size_t)n*2048 + k] = f2bf(v);
}
// token Wih; columns n = dir*624 + g*208 + j (j<200 real). bih folded at
// input col 100 (layer0) / 400 (layers 1,2). Rows prescaled for exp2 gates.
__global__ void k_build_wtok(const float* __restrict__ gw, const float* __restrict__ bih,
                             u16* __restrict__ out){
  size_t idx = (size_t)blockIdx.x*256 + threadIdx.x;
  if (idx >= (size_t)3*1280*416) return;
  int k = (int)(idx % 416);
  int n = (int)((idx/416) % 1280);
  int l = (int)(idx/(416*1280));
  float v = 0.f;
  int dir = -1, r = 0;
  if (n < 624){ dir = 0; r = n; }
  else if (n < 1248){ dir = 1; r = n - 624; }
  if (dir >= 0){
    int g = r / 208, j = r % 208;
    if (j < 200){
      int row = (l*2 + dir)*600 + g*200 + j;
      int kreal = (l == 0) ? 100 : 400;
      if (k < kreal)       v = gw[(size_t)row*400 + k];
      else if (k == kreal) v = bih[row];
      v *= (g == 2) ? GSC_N : GSC_RZ;
    }
  }
  out[idx] = f2bf(v);
}

// ---------- CSR ----------
__global__ void k_csr1(const int* __restrict__ dst, int* __restrict__ offs,
                       int* __restrict__ cursor){
  __shared__ int c0[2048];
  __shared__ int c1[2048];
  int tid = threadIdx.x; // 1024
  c0[tid] = 0; c0[tid+1024] = 0;
  __syncthreads();
  for (int e = tid; e < 16000; e += 1024) atomicAdd(&c0[dst[e]], 1);
  __syncthreads();
  int* s = c0; int* d = c1;
  for (int off = 1; off < 2048; off <<= 1){
    for (int i = tid; i < 2048; i += 1024){
      int v = s[i];
      if (i >= off) v += s[i-off];
      d[i] = v;
    }
    __syncthreads();
    int* tmp = s; s = d; d = tmp;
  }
  for (int i = tid; i < 2048; i += 1024){
    int ex = (i == 0) ? 0 : s[i-1];
    if (i <= 2000) offs[i] = ex;
    if (i < 2000)  cursor[i] = ex;
  }
}
__global__ void k_csr2(const int* __restrict__ src, const int* __restrict__ dst,
                       const int* __restrict__ et, int* __restrict__ cursor,
                       int* __restrict__ eidx){
  int e = blockIdx.x*256 + threadIdx.x;
  if (e >= 16000) return;
  int pos = atomicAdd(&cursor[dst[e]], 1);
  eidx[pos] = (src[e] << 1) | (et[e] & 1);
}

// ---------- GGNN pieces ----------
__global__ void k_init_h0(const float* __restrict__ feats, float* __restrict__ h,
                          u16* __restrict__ hb0){
  int j = blockIdx.x*256 + threadIdx.x;  // 0..2047
  int m = blockIdx.y;                    // 0..2047
  float v = (m < 2000 && j < 100) ? feats[(size_t)m*100 + j] : 0.f;
  if (m < 2000 && j < 2000) h[(size_t)m*2000 + j] = v;
  if (j < 128) hb0[(size_t)m*128 + j] = f2bf(v);
}
__global__ void k_gather(const float* __restrict__ C1, const int* __restrict__ offs,
                         const int* __restrict__ eidx, const float* __restrict__ gb,
                         u16* __restrict__ ab){
  int c = blockIdx.y*256 + threadIdx.x;  // 0..2047
  int n = blockIdx.x;                    // 0..2047
  float s = 0.f;
  if (n < 2000 && c < 2000){
    int p0 = offs[n], p1 = offs[n+1];
    for (int p = p0; p < p1; ++p){
      int pk = eidx[p];
      int sn = pk >> 1, e = pk & 1;
      s += C1[(size_t)sn*10112 + e*2000 + c] + gb[(size_t)e*2000 + c];
    }
  }
  ab[(size_t)n*2048 + c] = f2bf(s);
}
__global__ void k_gru_elem(const float* __restrict__ C1, const float* __restrict__ C2,
                           const float* __restrict__ bih, const float* __restrict__ bhh,
                           float* __restrict__ h, u16* __restrict__ hb){
  int j = blockIdx.x*256 + threadIdx.x;  // 0..2047
  int m = blockIdx.y;                    // 0..2047
  float hv = 0.f;
  if (m < 2000 && j < 2000){
    const float* c1 = C1 + (size_t)m*10112;
    const float* c2 = C2 + (size_t)m*6016;
    float gir = c2[j]        + bih[j];
    float giz = c2[2000 + j] + bih[2000 + j];
    float gin = c2[4000 + j] + bih[4000 + j];
    float ghr = c1[4000 + j] + bhh[j];
    float ghz = c1[6000 + j] + bhh[2000 + j];
    float ghn = c1[8000 + j] + bhh[4000 + j];
    float r  = sigm(gir + ghr);
    float z  = sigm(giz + ghz);
    float nn = tanh_(gin + r*ghn);
    float ho = h[(size_t)m*2000 + j];
    hv = (1.f - z)*nn + z*ho;
    h[(size_t)m*2000 + j] = hv;
  }
  hb[(size_t)m*2048 + j] = f2bf(hv);
}
__global__ void k_ranges(const int* __restrict__ batch, int* __restrict__ bstart){
  int i = blockIdx.x*1024 + threadIdx.x;
  if (i < 2000){
    int cur  = batch[i];
    int prev = (i == 0) ? -1 : batch[i-1];
    for (int b = prev+1; b <= cur; ++b) bstart[b] = i;
    if (i == 1999) for (int b = cur+1; b <= 16; ++b) bstart[b] = 2000;
  }
}
__global__ void k_segmax(const float* __restrict__ h, const int* __restrict__ bstart,
                         float* __restrict__ xhead){
  int j = blockIdx.x*256 + threadIdx.x;
  int b = blockIdx.y;
  if (j >= 2000) return;
  int n0 = bstart[b], n1 = bstart[b+1];
  float m = -3.0e38f;
  for (int n = n0; n < n1; ++n) m = fmaxf(m, h[(size_t)n*2000 + j]);
  xhead[(size_t)b*3200 + j] = m;
}

// ---------- token pieces ----------
__global__ void k_embed(const int* __restrict__ tokens, const float* __restrict__ emb,
                        u16* __restrict__ X){
  int k = blockIdx.x*256 + threadIdx.x;
  int row = blockIdx.y;                  // row = t*16+b
  if (k >= 416) return;
  int t = row >> 4, b = row & 15;
  int tok = tokens[b*256 + t];
  float v;
  if (k < 100)                    v = emb[(size_t)tok*100 + k];
  else if (k == 100 || k == 400)  v = 1.f;   // bias-one columns
  else                            v = 0.f;
  X[(size_t)row*416 + k] = f2bf(v);
}
__global__ void k_zeropad(u16* __restrict__ X){
  int r = blockIdx.x*16 + (threadIdx.x >> 4);
  int c = 400 + (threadIdx.x & 15);
  X[(size_t)r*416 + c] = (c == 400) ? (u16)0x3F80 : (u16)0;  // bias-one at 400
}

// Recurrent GRU: 2 WGs (dir), 13 waves each, 1 j-tile per wave.
// A = Whh fragments in registers (prescaled to exp2 domain; col 200 = bhh).
// B = h from LDS [b][k], k=200 is constant 1.0.
// v3: Gt in fp32 (zero-unpack: acc init = prefetch regs), fx4 packed gate math,
//     tanh = 1-2*rcp(e+1), raw barrier, double-buffered dwordx4 prefetch.
#define RSTEP(GC, GN, GNEXT, S)                                                   \
  {                                                                               \
    GN[0] = *(const fx4*)((GNEXT) + (0*208 + jb));                                \
    GN[1] = *(const fx4*)((GNEXT) + (1*208 + jb));                                \
    GN[2] = *(const fx4*)((GNEXT) + (2*208 + jb));                                \
    const int p_ = (S) & 1;                                                       \
    fx4 aR  = GC[0];                                                              \
    fx4 aZ  = GC[1];                                                              \
    const fx4 giN = GC[2];                                                        \
    fx4 aR1 = fx4{0.f,0.f,0.f,0.f}, aZ1 = fx4{0.f,0.f,0.f,0.f};                   \
    fx4 aN  = fx4{0.f,0.f,0.f,0.f}, aN1 = fx4{0.f,0.f,0.f,0.f};                   \
    const u16* hp = hBs + p_*16*HS + col*HS;                                      \
    _Pragma("unroll")                                                             \
    for (int ks = 0; ks < 7; ++ks){                                               \
      s16x8 bv = *(const s16x8*)(hp + ks*32 + quad*8);                            \
      if (ks & 1){                                                                \
        aR1 = mfma16(Af[0][ks], bv, aR1);                                         \
        aZ1 = mfma16(Af[1][ks], bv, aZ1);                                         \
        aN1 = mfma16(Af[2][ks], bv, aN1);                                         \
      } else {                                                                    \
        aR  = mfma16(Af[0][ks], bv, aR );                                         \
        aZ  = mfma16(Af[1][ks], bv, aZ );                                         \
        aN  = mfma16(Af[2][ks], bv, aN );                                         \
      }                                                                           \
    }                                                                             \
    aR += aR1; aZ += aZ1; aN += aN1;                                              \
    fx4 uR, uZ, rr, rz, ee, rn;                                                   \
    _Pragma("unroll")                                                             \
    for (int i = 0; i < 4; ++i){ uR[i] = exp2_(aR[i]); uZ[i] = exp2_(aZ[i]); }    \
    const fx4 one = fx4{1.f,1.f,1.f,1.f};                                         \
    fx4 dR = uR + one;                                                            \
    fx4 dZ = uZ + one;                                                            \
    _Pragma("unroll")                                                             \
    for (int i = 0; i < 4; ++i){ rr[i] = rcp_(dR[i]); rz[i] = rcp_(dZ[i]); }      \
    fx4 x = rr*aN + giN;                                                          \
    _Pragma("unroll")                                                             \
    for (int i = 0; i < 4; ++i){ x[i] = fminf(x[i], 100.f); ee[i] = exp2_(x[i]); }\
    fx4 dN = ee + one;                                                            \
    _Pragma("unroll")                                                             \
    for (int i = 0; i < 4; ++i){ rn[i] = rcp_(dN[i]); }                           \
    fx4 nn = one - 2.f*rn;                                                        \
    h = nn + rz*(h - nn);                                                         \
    if (jb < 200){                                                                \
      u32 d0 = cvt_pk_bf16(h[0], h[1]);                                           \
      u32 d1 = cvt_pk_bf16(h[2], h[3]);                                           \
      *(uint2*)(hBs + ((p_^1)*16 + col)*HS + jb) = make_uint2(d0, d1);            \
      if (writeX){                                                                \
        int t_ = dir ? (255 - (S)) : (S);                                         \
        *(uint2*)(Xout + (size_t)(t_*16 + col)*416 + dir*200 + jb) = make_uint2(d0, d1); \
      }                                                                           \
    }                                                                             \
    asm volatile("s_waitcnt lgkmcnt(0)" ::: "memory");                            \
    __builtin_amdgcn_s_barrier();                                                 \
    __builtin_amdgcn_sched_barrier(0);                                            \
  }

__global__ __launch_bounds__(832, 1) void k_recur(
    const float* __restrict__ Gt,    // [t][dir][b][624] fp32: r = g*208 + j (prescaled)
    const float* __restrict__ Whh,   // [3][2][600][200]
    const float* __restrict__ bhh,   // [3][2][600]
    u16* __restrict__ Xout,          // [4096][416] bf16
    float* __restrict__ xhead,       // [16][3200]
    int layer, int writeX)
{
  const int dir  = blockIdx.x;
  const int tid  = threadIdx.x;
  const int wv   = tid >> 6, lane = tid & 63;
  const int col  = lane & 15, quad = lane >> 4;
  constexpr int HS = 232;
  __shared__ u16 hBs[2*16*HS];
  for (int i = tid; i < 2*16*HS; i += 832) hBs[i] = 0;
  __syncthreads();
  if (tid < 32) hBs[(tid>>4)*16*HS + (tid&15)*HS + 200] = 0x3F80;  // k=200 -> 1.0

  const int jp = wv*16 + col;            // A-operand row (gate-output index)
  const int jb = wv*16 + quad*4;         // this lane's 4 h outputs
  s16x8 Af[3][7];
  const float* Wb = Whh + (size_t)(layer*2 + dir)*600*200;
  const float* bb = bhh + (size_t)(layer*2 + dir)*600;
#pragma unroll
  for (int g = 0; g < 3; ++g){
    const float gsc = (g == 2) ? GSC_N : GSC_RZ;
#pragma unroll
    for (int ks = 0; ks < 7; ++ks){
      s16x8 v;
#pragma unroll
      for (int ii = 0; ii < 8; ++ii){
        int k = ks*32 + quad*8 + ii;
        float w = 0.f;
        if (jp < 200){
          if (k < 200)        w = Wb[(size_t)(g*200 + jp)*200 + k];
          else if (k == 200)  w = bb[g*200 + jp];
        }
        v[ii] = (short)f2bf(w * gsc);
      }
      Af[g][ks] = v;
    }
  }
  __syncthreads();

  const int t0 = dir ? 255 : 0;
  const float* gb = Gt + ((size_t)(t0*2 + dir)*16 + col)*624;
  const ptrdiff_t dstep = dir ? -(ptrdiff_t)19968 : (ptrdiff_t)19968;

  fx4 h = fx4{0.f,0.f,0.f,0.f};
  fx4 g0[3], g1[3];
  // preload gi for step 0
  g0[0] = *(const fx4*)(gb + (0*208 + jb));
  g0[1] = *(const fx4*)(gb + (1*208 + jb));
  g0[2] = *(const fx4*)(gb + (2*208 + jb));

  for (int s = 0; s < 256; s += 2){
    RSTEP(g0, g1, gb + dstep,   s);      // even step: reads buf p=0, writes p=1
    RSTEP(g1, g0, gb + 2*dstep, s+1);    // odd step: reads p=1, writes p=0
    gb += 2*dstep;
  }

#pragma unroll
  for (int i = 0; i < 4; ++i){
    int j = jb + i;
    if (j < 200)
      xhead[(size_t)col*3200 + 2000 + (layer*2 + dir)*200 + j] = h[i];
  }
}

// ---------- head ----------
__global__ void k_head(const float* __restrict__ x, const float* __restrict__ W,
                       const float* __restrict__ bias, float* __restrict__ y,
                       int IN, int OUT){
  int o = blockIdx.x*16 + (threadIdx.x >> 4);
  int b = threadIdx.x & 15;
  if (o >= OUT) return;
  const float* xr = x + (size_t)b*IN;
  const float* wr = W + (size_t)o*IN;
  float s = 0.f;
  for (int k = 0; k < IN; k += 4){
    float4 xv = *(const float4*)(xr + k);
    float4 wv = *(const float4*)(wr + k);
    s += xv.x*wv.x + xv.y*wv.y + xv.z*wv.z + xv.w*wv.w;
  }
  s += bias[o];
  y[(size_t)b*OUT + o] = fmaxf(s, 0.f);
}
__global__ void k_zero_out(float* __restrict__ y, int n){
  int i = blockIdx.x*256 + threadIdx.x;
  if (i < n) y[i] = 0.f;
}

// ---------- workspace layout ----------
constexpr size_t S_WFUSED = (size_t)10112*2048*2;
constexpr size_t S_WIHT   = (size_t)6016*2048*2;
constexpr size_t S_WTOK   = (size_t)3*1280*416*2;
constexpr size_t S_HB     = (size_t)2048*2048*2;
constexpr size_t S_H      = (size_t)2000*2000*4;
constexpr size_t S_HB0    = (size_t)2048*128*2;
constexpr size_t S_C1     = (size_t)2048*10112*4;
constexpr size_t S_C2     = (size_t)2048*6016*4;   // also holds Gt fp32 (4096*1248*4 = 20.4 MB)
constexpr size_t S_X      = (size_t)4096*416*2;

constexpr size_t O_WFUSED = 0;
constexpr size_t O_WIHT   = O_WFUSED + S_WFUSED;
constexpr size_t O_WTOK   = O_WIHT + S_WIHT;
constexpr size_t O_HB     = O_WTOK + S_WTOK;
constexpr size_t O_AB     = O_HB + S_HB;
constexpr size_t O_H      = O_AB + S_HB;
constexpr size_t O_HB0    = O_H + S_H;
constexpr size_t O_C1     = O_HB0 + S_HB0;
constexpr size_t O_C2     = O_C1 + S_C1;
constexpr size_t O_XA     = O_C2 + S_C2;
constexpr size_t O_XB     = O_XA + S_X;
constexpr size_t O_OFFS   = O_XB + S_X;
constexpr size_t O_CUR    = O_OFFS + 2048*4;
constexpr size_t O_EIDX   = O_CUR + 2048*4;
constexpr size_t O_BST    = O_EIDX + 16384*4;
constexpr size_t O_XH     = O_BST + 256;
constexpr size_t O_B1     = O_XH + (size_t)16*3200*4;
constexpr size_t O_B2     = O_B1 + (size_t)16*1024*4;
constexpr size_t WS_NEEDED= O_B2 + (size_t)16*512*4;

extern "C" void kernel_launch(void* const* d_in, const int* in_sizes, int n_in,
                              void* d_out, int out_size, void* d_ws, size_t ws_size,
                              hipStream_t stream)
{
  const float* feats  = (const float*)d_in[0];
  const int*   tokens = (const int*)  d_in[1];
  const int*   esrc   = (const int*)  d_in[2];
  const int*   edst   = (const int*)  d_in[3];
  const int*   eet    = (const int*)  d_in[4];
  const int*   batch  = (const int*)  d_in[5];
  const float* embedw = (const float*)d_in[6];
  const float* gW     = (const float*)d_in[7];
  const float* gb     = (const float*)d_in[8];
  const float* gWih   = (const float*)d_in[9];
  const float* gWhh   = (const float*)d_in[10];
  const float* gbih   = (const float*)d_in[11];
  const float* gbhh   = (const float*)d_in[12];
  const float* tWih   = (const float*)d_in[13];
  const float* tWhh   = (const float*)d_in[14];
  const float* tbih   = (const float*)d_in[15];
  const float* tbhh   = (const float*)d_in[16];
  const float* l1W    = (const float*)d_in[17];
  const float* l1b    = (const float*)d_in[18];
  const float* l11W   = (const float*)d_in[19];
  const float* l11b   = (const float*)d_in[20];
  const float* l2W    = (const float*)d_in[21];
  const float* l2b    = (const float*)d_in[22];
  (void)in_sizes; (void)n_in;

  float* out = (float*)d_out;
  if (ws_size < WS_NEEDED){
    k_zero_out<<<1, 256, 0, stream>>>(out, out_size);
    return;
  }
  uint8_t* ws = (uint8_t*)d_ws;
  u16*   Wfused = (u16*)(ws + O_WFUSED);
  u16*   WihT   = (u16*)(ws + O_WIHT);
  u16*   Wtok   = (u16*)(ws + O_WTOK);
  u16*   HBm    = (u16*)(ws + O_HB);
  u16*   ABm    = (u16*)(ws + O_AB);
  float* Hm     = (float*)(ws + O_H);
  u16*   HB0    = (u16*)(ws + O_HB0);
  float* C1     = (float*)(ws + O_C1);
  float* C2     = (float*)(ws + O_C2);
  float* Gt     = (float*)(ws + O_C2);   // token gi, fp32 scatter layout (reuses C2)
  u16*   XA     = (u16*)(ws + O_XA);
  u16*   XB     = (u16*)(ws + O_XB);
  int*   OFFS   = (int*)(ws + O_OFFS);
  int*   CUR    = (int*)(ws + O_CUR);
  int*   EIDX   = (int*)(ws + O_EIDX);
  int*   BST    = (int*)(ws + O_BST);
  float* XH     = (float*)(ws + O_XH);
  float* B1     = (float*)(ws + O_B1);
  float* B2     = (float*)(ws + O_B2);

  // ---- prep ----
  k_build_wfused<<<dim3(8,10112), 256, 0, stream>>>(gW, gWhh, Wfused);
  k_build_wiht  <<<dim3(8,6016),  256, 0, stream>>>(gWih, WihT);
  k_build_wtok  <<<6240,          256, 0, stream>>>(tWih, tbih, Wtok);
  k_csr1        <<<1,            1024, 0, stream>>>(edst, OFFS, CUR);
  k_csr2        <<<63,            256, 0, stream>>>(esrc, edst, eet, CUR, EIDX);
  k_init_h0     <<<dim3(8,2048),  256, 0, stream>>>(feats, Hm, HB0);
  k_embed       <<<dim3(2,4096),  256, 0, stream>>>(tokens, embedw, XA);
  k_zeropad     <<<256,           256, 0, stream>>>(XB);

  // ---- GGNN: 3 steps ----
  for (int step = 0; step < 3; ++step){
    if (step == 0)
      gemm_bt<0><<<dim3(79,16), 256, 0, stream>>>(HB0, Wfused, C1, 128, 2048, 10112, 128);
    else
      gemm_bt<0><<<dim3(79,16), 256, 0, stream>>>(HBm, Wfused, C1, 2048, 2048, 10112, 2048);
    k_gather<<<dim3(2048,8), 256, 0, stream>>>(C1, OFFS, EIDX, gb, ABm);
    gemm_bt<0><<<dim3(47,16), 256, 0, stream>>>(ABm, WihT, C2, 2048, 2048, 6016, 2048);
    k_gru_elem<<<dim3(8,2048), 256, 0, stream>>>(C1, C2, gbih, gbhh, Hm, HBm);
  }
  k_ranges<<<2, 1024, 0, stream>>>(batch, BST);
  k_segmax<<<dim3(8,16), 256, 0, stream>>>(Hm, BST, XH);

  // ---- token branch: 3 bidirectional GRU layers ----
  gemm_bt<2><<<dim3(10,32), 256, 0, stream>>>(XA, Wtok + 0*(size_t)1280*416, Gt, 416, 416, 0, 128);
  k_recur<<<2, 832, 0, stream>>>(Gt, tWhh, tbhh, XB, XH, 0, 1);
  gemm_bt<2><<<dim3(10,32), 256, 0, stream>>>(XB, Wtok + 1*(size_t)1280*416, Gt, 416, 416, 0, 416);
  k_recur<<<2, 832, 0, stream>>>(Gt, tWhh, tbhh, XA, XH, 1, 1);
  gemm_bt<2><<<dim3(10,32), 256, 0, stream>>>(XA, Wtok + 2*(size_t)1280*416, Gt, 416, 416, 0, 416);
  k_recur<<<2, 832, 0, stream>>>(Gt, tWhh, tbhh, XB, XH, 2, 0);

  // ---- head ----
  k_head<<<63, 256, 0, stream>>>(XH, l1W, l1b, B1, 3200, 1000);
  k_head<<<32, 256, 0, stream>>>(B1, l11W, l11b, B2, 1000, 500);
  k_head<<<1,  256, 0, stream>>>(B2, l2W, l2b, out, 500, 2);
}

// Round 4
// 2398.034 us; speedup vs baseline: 1.4947x; 1.1218x over previous
//
#include <hip/hip_runtime.h>
#include <cstdint>
#include <cstddef>

typedef unsigned short u16;
typedef unsigned int   u32;
typedef __attribute__((ext_vector_type(8))) short s16x8;
typedef __attribute__((ext_vector_type(4))) float fx4;

// ---------- helpers ----------
__device__ __forceinline__ u16 f2bf(float x){
  u32 u = __float_as_uint(x);
  u32 r = (u + 0x7fffu + ((u >> 16) & 1u)) >> 16;   // RNE
  return (u16)r;
}
__device__ __forceinline__ float bf2f(u16 x){
  return __uint_as_float(((u32)x) << 16);
}
__device__ __forceinline__ float rcp_(float x){ return __builtin_amdgcn_rcpf(x); }
__device__ __forceinline__ float exp2_(float x){
  float r; asm("v_exp_f32 %0, %1" : "=v"(r) : "v"(x)); return r;
}
__device__ __forceinline__ float sigm(float x){ return rcp_(1.f + __expf(-x)); }
__device__ __forceinline__ float tanh_(float x){
  x = fminf(fmaxf(x, -15.f), 15.f);
  float e = __expf(2.f*x);
  return (e-1.f)*rcp_(e+1.f);
}
__device__ __forceinline__ u32 cvt_pk_bf16(float lo, float hi){
  u32 d;
  asm("v_cvt_pk_bf16_f32 %0, %1, %2" : "=v"(d) : "v"(lo), "v"(hi));
  return d;
}
__device__ __forceinline__ void gl_lds16(const u16* g, u16* l){
  __builtin_amdgcn_global_load_lds((__attribute__((address_space(1))) void*)(void*)g,
                                   (__attribute__((address_space(3))) void*)(void*)l,
                                   16, 0, 0);
}
__device__ __forceinline__ fx4 mfma16(s16x8 a, s16x8 b, fx4 c){
  return __builtin_amdgcn_mfma_f32_16x16x32_bf16(a, b, c, 0, 0, 0);
}

// gate prescale: r,z rows by -log2(e); n rows by 2*log2(e)  (exp2-domain gates)
#define GSC_RZ (-1.442695041f)
#define GSC_N  ( 2.885390082f)

// ---------- generic bf16 GEMM  C[M][N] = A[M][K] * Bt[N][K]^T  (m97 structure) ----------
// MODE 0: fp32 row-major C.  MODE 2: fp32 scatter into Gt[t][dir][b][624] token layout.
template<int MODE>
__global__ __launch_bounds__(256, 2) void gemm_bt(
    const u16* __restrict__ A, const u16* __restrict__ Bt, void* __restrict__ Cp,
    int lda, int ldb, int ldc, int K)
{
  __shared__ u16 As[128*32];
  __shared__ u16 Bs[128*32];
  const int t    = threadIdx.x;
  const int lane = t & 63;
  const int wave = t >> 6;
  const int mw   = (wave >> 1) * 64;
  const int nw   = (wave & 1) * 64;
  const int m0   = blockIdx.y * 128;
  const int n0   = blockIdx.x * 128;
  const int col  = lane & 15, quad = lane >> 4;

  fx4 acc[4][4];
#pragma unroll
  for (int i=0;i<4;i++)
#pragma unroll
    for (int j=0;j<4;j++) acc[i][j] = fx4{0.f,0.f,0.f,0.f};

  const int u0 = t, u1 = t + 256;
  const int ar0 = u0 >> 2, ac0 = (u0 & 3) * 8;
  const int ar1 = u1 >> 2, ac1 = (u1 & 3) * 8;
  const u16* gA0 = A  + (size_t)(m0 + ar0) * lda + ac0;
  const u16* gA1 = A  + (size_t)(m0 + ar1) * lda + ac1;
  const u16* gB0 = Bt + (size_t)(n0 + ar0) * ldb + ac0;
  const u16* gB1 = Bt + (size_t)(n0 + ar1) * ldb + ac1;
  u16* lA0 = As + u0*8; u16* lA1 = As + u1*8;
  u16* lB0 = Bs + u0*8; u16* lB1 = Bs + u1*8;
  const u16* pa = As + (mw + col)*32 + quad*8;
  const u16* pb = Bs + (nw + col)*32 + quad*8;

  for (int k0 = 0; k0 < K; k0 += 32){
    gl_lds16(gA0 + k0, lA0);
    gl_lds16(gA1 + k0, lA1);
    gl_lds16(gB0 + k0, lB0);
    gl_lds16(gB1 + k0, lB1);
    __syncthreads();
    s16x8 af[4], bf[4];
#pragma unroll
    for (int mt=0; mt<4; ++mt) af[mt] = *(const s16x8*)(pa + mt*512);
#pragma unroll
    for (int nt=0; nt<4; ++nt) bf[nt] = *(const s16x8*)(pb + nt*512);
#pragma unroll
    for (int mt=0; mt<4; ++mt)
#pragma unroll
      for (int nt=0; nt<4; ++nt)
        acc[mt][nt] = mfma16(af[mt], bf[nt], acc[mt][nt]);
    __syncthreads();
  }
#pragma unroll
  for (int mt=0; mt<4; ++mt)
#pragma unroll
    for (int nt=0; nt<4; ++nt)
#pragma unroll
      for (int i=0; i<4; ++i){
        int m = m0 + mw + mt*16 + quad*4 + i;
        int n = n0 + nw + nt*16 + col;
        float v = acc[mt][nt][i];
        if (MODE == 0){
          ((float*)Cp)[(size_t)m*ldc + n] = v;
        } else {
          if (n < 1248){
            int dir = (n >= 624) ? 1 : 0;
            int r   = n - dir*624;
            int tt  = m >> 4, b = m & 15;
            ((float*)Cp)[((size_t)((tt*2 + dir)*16 + b))*624 + r] = v;
          }
        }
      }
}

// ---------- weight prep ----------
__global__ void k_build_wfused(const float* __restrict__ gW, const float* __restrict__ gWhh,
                               u16* __restrict__ out){
  int k = blockIdx.x*256 + threadIdx.x;   // 0..2047
  int n = blockIdx.y;                     // 0..10111
  float v = 0.f;
  if (k < 2000){
    if (n < 4000)       v = gW  [(size_t)n*2000 + k];
    else if (n < 10000) v = gWhh[(size_t)(n-4000)*2000 + k];
  }
  out[(size_t)n*2048 + k] = f2bf(v);
}
__global__ void k_build_wiht(const float* __restrict__ W, u16* __restrict__ out){
  int k = blockIdx.x*256 + threadIdx.x;
  int n = blockIdx.y;                     // 0..6015
  float v = (k < 2000 && n < 6000) ? W[(size_t)n*2000 + k] : 0.f;
  out[(size_t)n*2048 + k] = f2bf(v);
}
// token Wih; columns n = dir*624 + g*208 + j (j<200 real). bih folded at
// input col 100 (layer0) / 400 (layers 1,2). Rows prescaled for exp2 gates.
__global__ void k_build_wtok(const float* __restrict__ gw, const float* __restrict__ bih,
                             u16* __restrict__ out){
  size_t idx = (size_t)blockIdx.x*256 + threadIdx.x;
  if (idx >= (size_t)3*1280*416) return;
  int k = (int)(idx % 416);
  int n = (int)((idx/416) % 1280);
  int l = (int)(idx/(416*1280));
  float v = 0.f;
  int dir = -1, r = 0;
  if (n < 624){ dir = 0; r = n; }
  else if (n < 1248){ dir = 1; r = n - 624; }
  if (dir >= 0){
    int g = r / 208, j = r % 208;
    if (j < 200){
      int row = (l*2 + dir)*600 + g*200 + j;
      int kreal = (l == 0) ? 100 : 400;
      if (k < kreal)       v = gw[(size_t)row*400 + k];
      else if (k == kreal) v = bih[row];
      v *= (g == 2) ? GSC_N : GSC_RZ;
    }
  }
  out[idx] = f2bf(v);
}

// ---------- CSR ----------
__global__ void k_csr1(const int* __restrict__ dst, int* __restrict__ offs,
                       int* __restrict__ cursor){
  __shared__ int c0[2048];
  __shared__ int c1[2048];
  int tid = threadIdx.x; // 1024
  c0[tid] = 0; c0[tid+1024] = 0;
  __syncthreads();
  for (int e = tid; e < 16000; e += 1024) atomicAdd(&c0[dst[e]], 1);
  __syncthreads();
  int* s = c0; int* d = c1;
  for (int off = 1; off < 2048; off <<= 1){
    for (int i = tid; i < 2048; i += 1024){
      int v = s[i];
      if (i >= off) v += s[i-off];
      d[i] = v;
    }
    __syncthreads();
    int* tmp = s; s = d; d = tmp;
  }
  for (int i = tid; i < 2048; i += 1024){
    int ex = (i == 0) ? 0 : s[i-1];
    if (i <= 2000) offs[i] = ex;
    if (i < 2000)  cursor[i] = ex;
  }
}
__global__ void k_csr2(const int* __restrict__ src, const int* __restrict__ dst,
                       const int* __restrict__ et, int* __restrict__ cursor,
                       int* __restrict__ eidx){
  int e = blockIdx.x*256 + threadIdx.x;
  if (e >= 16000) return;
  int pos = atomicAdd(&cursor[dst[e]], 1);
  eidx[pos] = (src[e] << 1) | (et[e] & 1);
}

// ---------- GGNN pieces ----------
__global__ void k_init_h0(const float* __restrict__ feats, float* __restrict__ h,
                          u16* __restrict__ hb0){
  int j = blockIdx.x*256 + threadIdx.x;  // 0..2047
  int m = blockIdx.y;                    // 0..2047
  float v = (m < 2000 && j < 100) ? feats[(size_t)m*100 + j] : 0.f;
  if (m < 2000 && j < 2000) h[(size_t)m*2000 + j] = v;
  if (j < 128) hb0[(size_t)m*128 + j] = f2bf(v);
}
__global__ void k_gather(const float* __restrict__ C1, const int* __restrict__ offs,
                         const int* __restrict__ eidx, const float* __restrict__ gb,
                         u16* __restrict__ ab){
  int c = blockIdx.y*256 + threadIdx.x;  // 0..2047
  int n = blockIdx.x;                    // 0..2047
  float s = 0.f;
  if (n < 2000 && c < 2000){
    int p0 = offs[n], p1 = offs[n+1];
    for (int p = p0; p < p1; ++p){
      int pk = eidx[p];
      int sn = pk >> 1, e = pk & 1;
      s += C1[(size_t)sn*10112 + e*2000 + c] + gb[(size_t)e*2000 + c];
    }
  }
  ab[(size_t)n*2048 + c] = f2bf(s);
}
__global__ void k_gru_elem(const float* __restrict__ C1, const float* __restrict__ C2,
                           const float* __restrict__ bih, const float* __restrict__ bhh,
                           float* __restrict__ h, u16* __restrict__ hb){
  int j = blockIdx.x*256 + threadIdx.x;  // 0..2047
  int m = blockIdx.y;                    // 0..2047
  float hv = 0.f;
  if (m < 2000 && j < 2000){
    const float* c1 = C1 + (size_t)m*10112;
    const float* c2 = C2 + (size_t)m*6016;
    float gir = c2[j]        + bih[j];
    float giz = c2[2000 + j] + bih[2000 + j];
    float gin = c2[4000 + j] + bih[4000 + j];
    float ghr = c1[4000 + j] + bhh[j];
    float ghz = c1[6000 + j] + bhh[2000 + j];
    float ghn = c1[8000 + j] + bhh[4000 + j];
    float r  = sigm(gir + ghr);
    float z  = sigm(giz + ghz);
    float nn = tanh_(gin + r*ghn);
    float ho = h[(size_t)m*2000 + j];
    hv = (1.f - z)*nn + z*ho;
    h[(size_t)m*2000 + j] = hv;
  }
  hb[(size_t)m*2048 + j] = f2bf(hv);
}
__global__ void k_ranges(const int* __restrict__ batch, int* __restrict__ bstart){
  int i = blockIdx.x*1024 + threadIdx.x;
  if (i < 2000){
    int cur  = batch[i];
    int prev = (i == 0) ? -1 : batch[i-1];
    for (int b = prev+1; b <= cur; ++b) bstart[b] = i;
    if (i == 1999) for (int b = cur+1; b <= 16; ++b) bstart[b] = 2000;
  }
}
__global__ void k_segmax(const float* __restrict__ h, const int* __restrict__ bstart,
                         float* __restrict__ xhead){
  int j = blockIdx.x*256 + threadIdx.x;
  int b = blockIdx.y;
  if (j >= 2000) return;
  int n0 = bstart[b], n1 = bstart[b+1];
  float m = -3.0e38f;
  for (int n = n0; n < n1; ++n) m = fmaxf(m, h[(size_t)n*2000 + j]);
  xhead[(size_t)b*3200 + j] = m;
}

// ---------- token pieces ----------
__global__ void k_embed(const int* __restrict__ tokens, const float* __restrict__ emb,
                        u16* __restrict__ X){
  int k = blockIdx.x*256 + threadIdx.x;
  int row = blockIdx.y;                  // row = t*16+b
  if (k >= 416) return;
  int t = row >> 4, b = row & 15;
  int tok = tokens[b*256 + t];
  float v;
  if (k < 100)                    v = emb[(size_t)tok*100 + k];
  else if (k == 100 || k == 400)  v = 1.f;   // bias-one columns
  else                            v = 0.f;
  X[(size_t)row*416 + k] = f2bf(v);
}
__global__ void k_zeropad(u16* __restrict__ X){
  int r = blockIdx.x*16 + (threadIdx.x >> 4);
  int c = 400 + (threadIdx.x & 15);
  X[(size_t)r*416 + c] = (c == 400) ? (u16)0x3F80 : (u16)0;  // bias-one at 400
}

// ---------- fused: recurrent GRU (blocks 0,1) + m97 GEMM tiles (blocks 2+) ----
// Recur role: identical to round-3 k_recur (13 waves, 1 j-tile/wave, fp32 Gt
// prefetch double-buffer, exp2-domain gates, raw barrier).
// GEMM role: 3 virtual 256-thread groups per block, each one m97 128x128 tile
// (MODE0 epilogue). Wave 12 + overflow groups only participate in barriers.
#define RSTEP(GC, GN, GNEXT, S)                                                   \
  {                                                                               \
    GN[0] = *(const fx4*)((GNEXT) + (0*208 + jb));                                \
    GN[1] = *(const fx4*)((GNEXT) + (1*208 + jb));                                \
    GN[2] = *(const fx4*)((GNEXT) + (2*208 + jb));                                \
    const int p_ = (S) & 1;                                                       \
    fx4 aR  = GC[0];                                                              \
    fx4 aZ  = GC[1];                                                              \
    const fx4 giN = GC[2];                                                        \
    fx4 aR1 = fx4{0.f,0.f,0.f,0.f}, aZ1 = fx4{0.f,0.f,0.f,0.f};                   \
    fx4 aN  = fx4{0.f,0.f,0.f,0.f}, aN1 = fx4{0.f,0.f,0.f,0.f};                   \
    const u16* hp = hBs + p_*16*HS + col*HS;                                      \
    _Pragma("unroll")                                                             \
    for (int ks = 0; ks < 7; ++ks){                                               \
      s16x8 bv = *(const s16x8*)(hp + ks*32 + quad*8);                            \
      if (ks & 1){                                                                \
        aR1 = mfma16(Af[0][ks], bv, aR1);                                         \
        aZ1 = mfma16(Af[1][ks], bv, aZ1);                                         \
        aN1 = mfma16(Af[2][ks], bv, aN1);                                         \
      } else {                                                                    \
        aR  = mfma16(Af[0][ks], bv, aR );                                         \
        aZ  = mfma16(Af[1][ks], bv, aZ );                                         \
        aN  = mfma16(Af[2][ks], bv, aN );                                         \
      }                                                                           \
    }                                                                             \
    aR += aR1; aZ += aZ1; aN += aN1;                                              \
    fx4 uR, uZ, rr, rz, ee, rn;                                                   \
    _Pragma("unroll")                                                             \
    for (int i = 0; i < 4; ++i){ uR[i] = exp2_(aR[i]); uZ[i] = exp2_(aZ[i]); }    \
    const fx4 one = fx4{1.f,1.f,1.f,1.f};                                         \
    fx4 dR = uR + one;                                                            \
    fx4 dZ = uZ + one;                                                            \
    _Pragma("unroll")                                                             \
    for (int i = 0; i < 4; ++i){ rr[i] = rcp_(dR[i]); rz[i] = rcp_(dZ[i]); }      \
    fx4 x = rr*aN + giN;                                                          \
    _Pragma("unroll")                                                             \
    for (int i = 0; i < 4; ++i){ x[i] = fminf(x[i], 100.f); ee[i] = exp2_(x[i]); }\
    fx4 dN = ee + one;                                                            \
    _Pragma("unroll")                                                             \
    for (int i = 0; i < 4; ++i){ rn[i] = rcp_(dN[i]); }                           \
    fx4 nn = one - 2.f*rn;                                                        \
    h = nn + rz*(h - nn);                                                         \
    if (jb < 200){                                                                \
      u32 d0 = cvt_pk_bf16(h[0], h[1]);                                           \
      u32 d1 = cvt_pk_bf16(h[2], h[3]);                                           \
      *(uint2*)(hBs + ((p_^1)*16 + col)*HS + jb) = make_uint2(d0, d1);            \
      if (writeX){                                                                \
        int t_ = dir ? (255 - (S)) : (S);                                         \
        *(uint2*)(Xout + (size_t)(t_*16 + col)*416 + dir*200 + jb) = make_uint2(d0, d1); \
      }                                                                           \
    }                                                                             \
    asm volatile("s_waitcnt lgkmcnt(0)" ::: "memory");                            \
    __builtin_amdgcn_s_barrier();                                                 \
    __builtin_amdgcn_sched_barrier(0);                                            \
  }

__global__ __launch_bounds__(832, 1) void k_fused(
    const float* __restrict__ Gt,    // [t][dir][b][624] fp32 (prescaled)
    const float* __restrict__ Whh,   // [3][2][600][200]
    const float* __restrict__ bhh,   // [3][2][600]
    u16* __restrict__ Xout,          // [4096][416] bf16
    float* __restrict__ xhead,       // [16][3200]
    int layer, int writeX,
    const u16* __restrict__ GA, const u16* __restrict__ GB,
    float* __restrict__ GC, int lda, int ldb, int ldc, int K,
    int ntiles, int gxd)
{
  constexpr int HS = 232;
  __shared__ u16 hBs[2*16*HS];        // 14848 B (recur role)
  __shared__ u16 GAs[3][128*32];      // 24576 B (gemm role)
  __shared__ u16 GBs[3][128*32];      // 24576 B
  const int tid = threadIdx.x;

  if (blockIdx.x < 2){
    // ================= recur role =================
    const int dir  = blockIdx.x;
    const int wv   = tid >> 6, lane = tid & 63;
    const int col  = lane & 15, quad = lane >> 4;
    for (int i = tid; i < 2*16*HS; i += 832) hBs[i] = 0;
    __syncthreads();
    if (tid < 32) hBs[(tid>>4)*16*HS + (tid&15)*HS + 200] = 0x3F80;  // k=200 -> 1.0

    const int jp = wv*16 + col;            // A-operand row (gate-output index)
    const int jb = wv*16 + quad*4;         // this lane's 4 h outputs
    s16x8 Af[3][7];
    const float* Wb = Whh + (size_t)(layer*2 + dir)*600*200;
    const float* bb = bhh + (size_t)(layer*2 + dir)*600;
#pragma unroll
    for (int g = 0; g < 3; ++g){
      const float gsc = (g == 2) ? GSC_N : GSC_RZ;
#pragma unroll
      for (int ks = 0; ks < 7; ++ks){
        s16x8 v;
#pragma unroll
        for (int ii = 0; ii < 8; ++ii){
          int k = ks*32 + quad*8 + ii;
          float w = 0.f;
          if (jp < 200){
            if (k < 200)        w = Wb[(size_t)(g*200 + jp)*200 + k];
            else if (k == 200)  w = bb[g*200 + jp];
          }
          v[ii] = (short)f2bf(w * gsc);
        }
        Af[g][ks] = v;
      }
    }
    __syncthreads();

    const int t0 = dir ? 255 : 0;
    const float* gb = Gt + ((size_t)(t0*2 + dir)*16 + col)*624;
    const ptrdiff_t dstep = dir ? -(ptrdiff_t)19968 : (ptrdiff_t)19968;

    fx4 h = fx4{0.f,0.f,0.f,0.f};
    fx4 g0[3], g1[3];
    g0[0] = *(const fx4*)(gb + (0*208 + jb));
    g0[1] = *(const fx4*)(gb + (1*208 + jb));
    g0[2] = *(const fx4*)(gb + (2*208 + jb));

    for (int s = 0; s < 256; s += 2){
      RSTEP(g0, g1, gb + dstep,   s);
      RSTEP(g1, g0, gb + 2*dstep, s+1);
      gb += 2*dstep;
    }

#pragma unroll
    for (int i = 0; i < 4; ++i){
      int j = jb + i;
      if (j < 200)
        xhead[(size_t)col*3200 + 2000 + (layer*2 + dir)*200 + j] = h[i];
    }
  } else {
    // ================= gemm role (3 tiles / block) =================
    const int bg = (int)blockIdx.x - 2;
    const int vg = tid >> 8;            // 0..3 (3 == idle wave 12)
    const int lt = tid & 255;
    int tt = bg*3 + vg;
    const bool act = (vg < 3) && (tt < ntiles);
    const int vgc = (vg < 3) ? vg : 0;
    if (!act) tt = 0;
    const int bx = tt % gxd, by = tt / gxd;
    const int lane = lt & 63;
    const int wave = lt >> 6;
    const int mw   = (wave >> 1) * 64;
    const int nw   = (wave & 1) * 64;
    const int m0   = by * 128;
    const int n0   = bx * 128;
    const int col  = lane & 15, quad = lane >> 4;

    fx4 acc[4][4];
#pragma unroll
    for (int i=0;i<4;i++)
#pragma unroll
      for (int j=0;j<4;j++) acc[i][j] = fx4{0.f,0.f,0.f,0.f};

    const int u0 = lt, u1 = lt + 256;
    const int ar0 = u0 >> 2, ac0 = (u0 & 3) * 8;
    const int ar1 = u1 >> 2, ac1 = (u1 & 3) * 8;
    const u16* gA0 = GA + (size_t)(m0 + ar0) * lda + ac0;
    const u16* gA1 = GA + (size_t)(m0 + ar1) * lda + ac1;
    const u16* gB0 = GB + (size_t)(n0 + ar0) * ldb + ac0;
    const u16* gB1 = GB + (size_t)(n0 + ar1) * ldb + ac1;
    u16* As = GAs[vgc];
    u16* Bs = GBs[vgc];
    u16* lA0 = As + u0*8; u16* lA1 = As + u1*8;
    u16* lB0 = Bs + u0*8; u16* lB1 = Bs + u1*8;
    const u16* pa = As + (mw + col)*32 + quad*8;
    const u16* pb = Bs + (nw + col)*32 + quad*8;

    for (int k0 = 0; k0 < K; k0 += 32){
      if (act){
        gl_lds16(gA0 + k0, lA0);
        gl_lds16(gA1 + k0, lA1);
        gl_lds16(gB0 + k0, lB0);
        gl_lds16(gB1 + k0, lB1);
      }
      __syncthreads();
      if (act){
        s16x8 af[4], bf[4];
#pragma unroll
        for (int mt=0; mt<4; ++mt) af[mt] = *(const s16x8*)(pa + mt*512);
#pragma unroll
        for (int nt=0; nt<4; ++nt) bf[nt] = *(const s16x8*)(pb + nt*512);
#pragma unroll
        for (int mt=0; mt<4; ++mt)
#pragma unroll
          for (int nt=0; nt<4; ++nt)
            acc[mt][nt] = mfma16(af[mt], bf[nt], acc[mt][nt]);
      }
      __syncthreads();
    }
    if (act){
#pragma unroll
      for (int mt=0; mt<4; ++mt)
#pragma unroll
        for (int nt=0; nt<4; ++nt)
#pragma unroll
          for (int i=0; i<4; ++i){
            int m = m0 + mw + mt*16 + quad*4 + i;
            int n = n0 + nw + nt*16 + col;
            GC[(size_t)m*ldc + n] = acc[mt][nt][i];
          }
    }
  }
}

// ---------- head ----------
__global__ void k_head(const float* __restrict__ x, const float* __restrict__ W,
                       const float* __restrict__ bias, float* __restrict__ y,
                       int IN, int OUT){
  int o = blockIdx.x*16 + (threadIdx.x >> 4);
  int b = threadIdx.x & 15;
  if (o >= OUT) return;
  const float* xr = x + (size_t)b*IN;
  const float* wr = W + (size_t)o*IN;
  float s = 0.f;
  for (int k = 0; k < IN; k += 4){
    float4 xv = *(const float4*)(xr + k);
    float4 wv = *(const float4*)(wr + k);
    s += xv.x*wv.x + xv.y*wv.y + xv.z*wv.z + xv.w*wv.w;
  }
  s += bias[o];
  y[(size_t)b*OUT + o] = fmaxf(s, 0.f);
}
__global__ void k_zero_out(float* __restrict__ y, int n){
  int i = blockIdx.x*256 + threadIdx.x;
  if (i < n) y[i] = 0.f;
}

// ---------- workspace layout ----------
constexpr size_t S_WFUSED = (size_t)10112*2048*2;
constexpr size_t S_WIHT   = (size_t)6016*2048*2;
constexpr size_t S_WTOK   = (size_t)3*1280*416*2;
constexpr size_t S_HB     = (size_t)2048*2048*2;
constexpr size_t S_H      = (size_t)2000*2000*4;
constexpr size_t S_HB0    = (size_t)2048*128*2;
constexpr size_t S_C1     = (size_t)2048*10112*4;
constexpr size_t S_C2     = (size_t)2048*6016*4;   // also holds Gt fp32 (aliased; schedule keeps uses disjoint)
constexpr size_t S_X      = (size_t)4096*416*2;

constexpr size_t O_WFUSED = 0;
constexpr size_t O_WIHT   = O_WFUSED + S_WFUSED;
constexpr size_t O_WTOK   = O_WIHT + S_WIHT;
constexpr size_t O_HB     = O_WTOK + S_WTOK;
constexpr size_t O_AB     = O_HB + S_HB;
constexpr size_t O_H      = O_AB + S_HB;
constexpr size_t O_HB0    = O_H + S_H;
constexpr size_t O_C1     = O_HB0 + S_HB0;
constexpr size_t O_C2     = O_C1 + S_C1;
constexpr size_t O_XA     = O_C2 + S_C2;
constexpr size_t O_XB     = O_XA + S_X;
constexpr size_t O_OFFS   = O_XB + S_X;
constexpr size_t O_CUR    = O_OFFS + 2048*4;
constexpr size_t O_EIDX   = O_CUR + 2048*4;
constexpr size_t O_BST    = O_EIDX + 16384*4;
constexpr size_t O_XH     = O_BST + 256;
constexpr size_t O_B1     = O_XH + (size_t)16*3200*4;
constexpr size_t O_B2     = O_B1 + (size_t)16*1024*4;
constexpr size_t WS_NEEDED= O_B2 + (size_t)16*512*4;

extern "C" void kernel_launch(void* const* d_in, const int* in_sizes, int n_in,
                              void* d_out, int out_size, void* d_ws, size_t ws_size,
                              hipStream_t stream)
{
  const float* feats  = (const float*)d_in[0];
  const int*   tokens = (const int*)  d_in[1];
  const int*   esrc   = (const int*)  d_in[2];
  const int*   edst   = (const int*)  d_in[3];
  const int*   eet    = (const int*)  d_in[4];
  const int*   batch  = (const int*)  d_in[5];
  const float* embedw = (const float*)d_in[6];
  const float* gW     = (const float*)d_in[7];
  const float* gb     = (const float*)d_in[8];
  const float* gWih   = (const float*)d_in[9];
  const float* gWhh   = (const float*)d_in[10];
  const float* gbih   = (const float*)d_in[11];
  const float* gbhh   = (const float*)d_in[12];
  const float* tWih   = (const float*)d_in[13];
  const float* tWhh   = (const float*)d_in[14];
  const float* tbih   = (const float*)d_in[15];
  const float* tbhh   = (const float*)d_in[16];
  const float* l1W    = (const float*)d_in[17];
  const float* l1b    = (const float*)d_in[18];
  const float* l11W   = (const float*)d_in[19];
  const float* l11b   = (const float*)d_in[20];
  const float* l2W    = (const float*)d_in[21];
  const float* l2b    = (const float*)d_in[22];
  (void)in_sizes; (void)n_in;

  float* out = (float*)d_out;
  if (ws_size < WS_NEEDED){
    k_zero_out<<<1, 256, 0, stream>>>(out, out_size);
    return;
  }
  uint8_t* ws = (uint8_t*)d_ws;
  u16*   Wfused = (u16*)(ws + O_WFUSED);
  u16*   WihT   = (u16*)(ws + O_WIHT);
  u16*   Wtok   = (u16*)(ws + O_WTOK);
  u16*   HBm    = (u16*)(ws + O_HB);
  u16*   ABm    = (u16*)(ws + O_AB);
  float* Hm     = (float*)(ws + O_H);
  u16*   HB0    = (u16*)(ws + O_HB0);
  float* C1     = (float*)(ws + O_C1);
  float* C2     = (float*)(ws + O_C2);
  float* Gt     = (float*)(ws + O_C2);   // token gi, fp32 scatter layout (aliased with C2)
  u16*   XA     = (u16*)(ws + O_XA);
  u16*   XB     = (u16*)(ws + O_XB);
  int*   OFFS   = (int*)(ws + O_OFFS);
  int*   CUR    = (int*)(ws + O_CUR);
  int*   EIDX   = (int*)(ws + O_EIDX);
  int*   BST    = (int*)(ws + O_BST);
  float* XH     = (float*)(ws + O_XH);
  float* B1     = (float*)(ws + O_B1);
  float* B2     = (float*)(ws + O_B2);

  // ---- prep ----
  k_build_wfused<<<dim3(8,10112), 256, 0, stream>>>(gW, gWhh, Wfused);
  k_build_wiht  <<<dim3(8,6016),  256, 0, stream>>>(gWih, WihT);
  k_build_wtok  <<<6240,          256, 0, stream>>>(tWih, tbih, Wtok);
  k_csr1        <<<1,            1024, 0, stream>>>(edst, OFFS, CUR);
  k_csr2        <<<63,            256, 0, stream>>>(esrc, edst, eet, CUR, EIDX);
  k_init_h0     <<<dim3(8,2048),  256, 0, stream>>>(feats, Hm, HB0);
  k_embed       <<<dim3(2,4096),  256, 0, stream>>>(tokens, embedw, XA);
  k_zeropad     <<<256,           256, 0, stream>>>(XB);
  k_ranges      <<<2,            1024, 0, stream>>>(batch, BST);

  // ---- interleaved: token recur (2 blocks) ∥ GGNN gemm1 (422 blocks) ----
  // token gi for layer 0
  gemm_bt<2><<<dim3(10,32), 256, 0, stream>>>(XA, Wtok + 0*(size_t)1280*416, Gt, 416, 416, 0, 128);
  // F1: recur layer0 ∥ gemm1 step0 (K=128)
  k_fused<<<424, 832, 0, stream>>>(Gt, tWhh, tbhh, XB, XH, 0, 1,
                                   HB0, Wfused, C1, 128, 2048, 10112, 128, 1264, 79);
  k_gather<<<dim3(2048,8), 256, 0, stream>>>(C1, OFFS, EIDX, gb, ABm);
  gemm_bt<0><<<dim3(47,16), 256, 0, stream>>>(ABm, WihT, C2, 2048, 2048, 6016, 2048);
  k_gru_elem<<<dim3(8,2048), 256, 0, stream>>>(C1, C2, gbih, gbhh, Hm, HBm);
  gemm_bt<2><<<dim3(10,32), 256, 0, stream>>>(XB, Wtok + 1*(size_t)1280*416, Gt, 416, 416, 0, 416);
  // F2: recur layer1 ∥ gemm1 step1 (K=2048)
  k_fused<<<424, 832, 0, stream>>>(Gt, tWhh, tbhh, XA, XH, 1, 1,
                                   HBm, Wfused, C1, 2048, 2048, 10112, 2048, 1264, 79);
  k_gather<<<dim3(2048,8), 256, 0, stream>>>(C1, OFFS, EIDX, gb, ABm);
  gemm_bt<0><<<dim3(47,16), 256, 0, stream>>>(ABm, WihT, C2, 2048, 2048, 6016, 2048);
  k_gru_elem<<<dim3(8,2048), 256, 0, stream>>>(C1, C2, gbih, gbhh, Hm, HBm);
  gemm_bt<2><<<dim3(10,32), 256, 0, stream>>>(XA, Wtok + 2*(size_t)1280*416, Gt, 416, 416, 0, 416);
  // F3: recur layer2 ∥ gemm1 step2 (K=2048)
  k_fused<<<424, 832, 0, stream>>>(Gt, tWhh, tbhh, XB, XH, 2, 0,
                                   HBm, Wfused, C1, 2048, 2048, 10112, 2048, 1264, 79);
  k_gather<<<dim3(2048,8), 256, 0, stream>>>(C1, OFFS, EIDX, gb, ABm);
  gemm_bt<0><<<dim3(47,16), 256, 0, stream>>>(ABm, WihT, C2, 2048, 2048, 6016, 2048);
  k_gru_elem<<<dim3(8,2048), 256, 0, stream>>>(C1, C2, gbih, gbhh, Hm, HBm);

  k_segmax<<<dim3(8,16), 256, 0, stream>>>(Hm, BST, XH);

  // ---- head ----
  k_head<<<63, 256, 0, stream>>>(XH, l1W, l1b, B1, 3200, 1000);
  k_head<<<32, 256, 0, stream>>>(B1, l11W, l11b, B2, 1000, 500);
  k_head<<<1,  256, 0, stream>>>(B2, l2W, l2b, out, 500, 2);
}